// Round 1
// baseline (6411.444 us; speedup 1.0000x reference)
//
#include <hip/hip_runtime.h>
#include <math.h>

// ============================================================================
// MAEEG classification, round 1: correct fp32 baseline.
//   conv encoder (3x conv1d stride2 K15 + GroupNorm(128 grp) + exact GELU)
//   -> transpose + sinusoidal pos enc
//   -> 4x transformer layer (MHA 8 heads x 32d over S=512, post-LN, FF 1024)
//   -> classifier: [32,131072] @ Wc1^T -> relu -> @ Wc2^T -> sigmoid
// All GEMM-shaped work through a 128x128x16 LDS-tiled SGEMM (8x8 micro-tile,
// float4 LDS reads + float4 stores). Convs are implicit GEMM (gathered B).
// Attention: one lane = one q row, online softmax, K/V rows via wave-uniform
// 128B loads. Classifier: split-K, Wc1 read exactly once from HBM.
// ws usage: 136.3 MB (A 67.1 | B 33.6 | C 16.8 | D 16.8 | PART 2.1 | HID)
// ============================================================================

#define BM 128
#define BN 128
#define BKK 16
#define LPAD 4  // LDS row pad (floats), keeps float4 alignment

// ---------------------------------------------------------------------------
// block-wide sum over 256 threads (4 waves)
__device__ __forceinline__ float maeeg_block_sum(float v, float* sc4) {
#pragma unroll
    for (int off = 32; off; off >>= 1) v += __shfl_down(v, off);
    int t = threadIdx.x;
    if ((t & 63) == 0) sc4[t >> 6] = v;
    __syncthreads();
    float r = sc4[0] + sc4[1] + sc4[2] + sc4[3];
    __syncthreads();
    return r;
}

// ---------------------------------------------------------------------------
// FC: out[M,N] = in[M,K] @ W[N,K]^T (+bias[N]) (+res[M,N]) (optional relu)
// grid (M/128, N/128), block 256.  K % 16 == 0, M,N % 128 == 0.
__global__ __launch_bounds__(256) void maeeg_fc_kernel(
    const float* __restrict__ in, const float* __restrict__ W,
    const float* __restrict__ bias, const float* __restrict__ res,
    float* __restrict__ out, int N, int K, int relu)
{
    __shared__ __align__(16) float As[BKK][BM + LPAD];
    __shared__ __align__(16) float Bs[BKK][BN + LPAD];
    const int m0 = blockIdx.x * BM, n0 = blockIdx.y * BN;
    const int t = threadIdx.x;
    const int tx = t & 15, ty = t >> 4;
    const int tf = t & 3, tm = t >> 2;  // staging: float4 col, row

    float acc[8][8];
#pragma unroll
    for (int i = 0; i < 8; ++i)
#pragma unroll
        for (int j = 0; j < 8; ++j) acc[i][j] = 0.f;

    for (int k0 = 0; k0 < K; k0 += BKK) {
        // stage A tile (rows tm, tm+64), 16 k as 4 float4s per row
        float4 av0 = ((const float4*)&in[(size_t)(m0 + tm) * K + k0])[tf];
        float4 av1 = ((const float4*)&in[(size_t)(m0 + tm + 64) * K + k0])[tf];
        float4 bv0 = ((const float4*)&W[(size_t)(n0 + tm) * K + k0])[tf];
        float4 bv1 = ((const float4*)&W[(size_t)(n0 + tm + 64) * K + k0])[tf];
        As[tf * 4 + 0][tm] = av0.x; As[tf * 4 + 1][tm] = av0.y;
        As[tf * 4 + 2][tm] = av0.z; As[tf * 4 + 3][tm] = av0.w;
        As[tf * 4 + 0][tm + 64] = av1.x; As[tf * 4 + 1][tm + 64] = av1.y;
        As[tf * 4 + 2][tm + 64] = av1.z; As[tf * 4 + 3][tm + 64] = av1.w;
        Bs[tf * 4 + 0][tm] = bv0.x; Bs[tf * 4 + 1][tm] = bv0.y;
        Bs[tf * 4 + 2][tm] = bv0.z; Bs[tf * 4 + 3][tm] = bv0.w;
        Bs[tf * 4 + 0][tm + 64] = bv1.x; Bs[tf * 4 + 1][tm + 64] = bv1.y;
        Bs[tf * 4 + 2][tm + 64] = bv1.z; Bs[tf * 4 + 3][tm + 64] = bv1.w;
        __syncthreads();
#pragma unroll
        for (int kk = 0; kk < BKK; ++kk) {
            const float4* Ar = (const float4*)&As[kk][0];
            const float4* Br = (const float4*)&Bs[kk][0];
            float4 a0 = Ar[ty], a1 = Ar[16 + ty];
            float4 b0 = Br[tx], b1 = Br[16 + tx];
            float av[8] = {a0.x, a0.y, a0.z, a0.w, a1.x, a1.y, a1.z, a1.w};
            float bv[8] = {b0.x, b0.y, b0.z, b0.w, b1.x, b1.y, b1.z, b1.w};
#pragma unroll
            for (int i = 0; i < 8; ++i)
#pragma unroll
                for (int j = 0; j < 8; ++j) acc[i][j] += av[i] * bv[j];
        }
        __syncthreads();
    }

    float4 bia0 = make_float4(0.f, 0.f, 0.f, 0.f), bia1 = bia0;
    if (bias) {
        bia0 = ((const float4*)(bias + n0))[tx];
        bia1 = ((const float4*)(bias + n0))[16 + tx];
    }
#pragma unroll
    for (int i = 0; i < 8; ++i) {
        int m = m0 + ((i < 4) ? (ty * 4 + i) : (64 + ty * 4 + i - 4));
        float4 r0 = make_float4(acc[i][0] + bia0.x, acc[i][1] + bia0.y,
                                acc[i][2] + bia0.z, acc[i][3] + bia0.w);
        float4 r1 = make_float4(acc[i][4] + bia1.x, acc[i][5] + bia1.y,
                                acc[i][6] + bia1.z, acc[i][7] + bia1.w);
        if (res) {
            float4 e0 = ((const float4*)&res[(size_t)m * N + n0])[tx];
            float4 e1 = ((const float4*)&res[(size_t)m * N + n0])[16 + tx];
            r0.x += e0.x; r0.y += e0.y; r0.z += e0.z; r0.w += e0.w;
            r1.x += e1.x; r1.y += e1.y; r1.z += e1.z; r1.w += e1.w;
        }
        if (relu) {
            r0.x = fmaxf(r0.x, 0.f); r0.y = fmaxf(r0.y, 0.f);
            r0.z = fmaxf(r0.z, 0.f); r0.w = fmaxf(r0.w, 0.f);
            r1.x = fmaxf(r1.x, 0.f); r1.y = fmaxf(r1.y, 0.f);
            r1.z = fmaxf(r1.z, 0.f); r1.w = fmaxf(r1.w, 0.f);
        }
        ((float4*)&out[(size_t)m * N + n0])[tx] = r0;
        ((float4*)&out[(size_t)m * N + n0])[16 + tx] = r1;
    }
}

// ---------------------------------------------------------------------------
// implicit-GEMM conv1d, stride 2, K=15, pad 7.
// out[b][o][t] = cb[o] + sum_{q} w[o*K3+q] * in[b][q/15][2t-7+q%15]
// grid (256/BM=2, len_out/BN, B), block 256.  K3 = CIN*15 (% 16 == 0).
__global__ __launch_bounds__(256) void maeeg_conv_kernel(
    const float* __restrict__ in, const float* __restrict__ w,
    const float* __restrict__ cb, float* __restrict__ out,
    int CIN, int len_in, int len_out)
{
    const int K3 = CIN * 15;
    __shared__ __align__(16) float As[BKK][BM + LPAD];
    __shared__ __align__(16) float Bs[BKK][BN + LPAD];
    const int o0 = blockIdx.x * BM, t0 = blockIdx.y * BN, b = blockIdx.z;
    const float* inb = in + (size_t)b * CIN * len_in;
    const int t = threadIdx.x;
    const int tx = t & 15, ty = t >> 4;
    const int tf = t & 3, tm = t >> 2;

    float acc[8][8];
#pragma unroll
    for (int i = 0; i < 8; ++i)
#pragma unroll
        for (int j = 0; j < 8; ++j) acc[i][j] = 0.f;

    for (int k0 = 0; k0 < K3; k0 += BKK) {
        // A tile: weight rows (contiguous over (ci,k))
        float4 av0 = ((const float4*)&w[(size_t)(o0 + tm) * K3 + k0])[tf];
        float4 av1 = ((const float4*)&w[(size_t)(o0 + tm + 64) * K3 + k0])[tf];
        As[tf * 4 + 0][tm] = av0.x; As[tf * 4 + 1][tm] = av0.y;
        As[tf * 4 + 2][tm] = av0.z; As[tf * 4 + 3][tm] = av0.w;
        As[tf * 4 + 0][tm + 64] = av1.x; As[tf * 4 + 1][tm + 64] = av1.y;
        As[tf * 4 + 2][tm + 64] = av1.z; As[tf * 4 + 3][tm + 64] = av1.w;
        // B tile: gathered input (virtual im2col), zero-padded at edges
#pragma unroll
        for (int i = 0; i < 8; ++i) {
            int e = t + i * 256;
            int kk = e & 15, tt = e >> 4;
            int qq = k0 + kk;
            int ci = qq / 15;
            int r = qq - ci * 15;
            int pos = 2 * (t0 + tt) - 7 + r;
            Bs[kk][tt] = ((unsigned)pos < (unsigned)len_in)
                             ? inb[(size_t)ci * len_in + pos] : 0.f;
        }
        __syncthreads();
#pragma unroll
        for (int kk = 0; kk < BKK; ++kk) {
            const float4* Ar = (const float4*)&As[kk][0];
            const float4* Br = (const float4*)&Bs[kk][0];
            float4 a0 = Ar[ty], a1 = Ar[16 + ty];
            float4 b0 = Br[tx], b1 = Br[16 + tx];
            float av[8] = {a0.x, a0.y, a0.z, a0.w, a1.x, a1.y, a1.z, a1.w};
            float bv[8] = {b0.x, b0.y, b0.z, b0.w, b1.x, b1.y, b1.z, b1.w};
#pragma unroll
            for (int i = 0; i < 8; ++i)
#pragma unroll
                for (int j = 0; j < 8; ++j) acc[i][j] += av[i] * bv[j];
        }
        __syncthreads();
    }
#pragma unroll
    for (int i = 0; i < 8; ++i) {
        int o = o0 + ((i < 4) ? (ty * 4 + i) : (64 + ty * 4 + i - 4));
        float bb = cb[o];
        float4 r0 = make_float4(acc[i][0] + bb, acc[i][1] + bb,
                                acc[i][2] + bb, acc[i][3] + bb);
        float4 r1 = make_float4(acc[i][4] + bb, acc[i][5] + bb,
                                acc[i][6] + bb, acc[i][7] + bb);
        float* op = out + ((size_t)b * 256 + o) * len_out + t0;
        ((float4*)op)[tx] = r0;
        ((float4*)op)[16 + tx] = r1;
    }
}

// ---------------------------------------------------------------------------
// GroupNorm (2 channels per group) + exact GELU, in place.
// grid (128 groups, B), block 256.
__global__ __launch_bounds__(256) void maeeg_gn_gelu_kernel(
    float* __restrict__ h, const float* __restrict__ g,
    const float* __restrict__ bta, int len)
{
    const int grp = blockIdx.x, b = blockIdx.y;
    float* p = h + ((size_t)b * 256 + grp * 2) * len;
    const int n = 2 * len;
    float s1 = 0.f, s2 = 0.f;
    for (int i = threadIdx.x; i < n; i += 256) {
        float v = p[i];
        s1 += v; s2 += v * v;
    }
    __shared__ float sc[4];
    float S1 = maeeg_block_sum(s1, sc);
    float S2 = maeeg_block_sum(s2, sc);
    float mu = S1 / (float)n;
    float var = fmaxf(S2 / (float)n - mu * mu, 0.f);
    float rs = rsqrtf(var + 1e-5f);
    float g0 = g[grp * 2], g1 = g[grp * 2 + 1];
    float b0 = bta[grp * 2], b1 = bta[grp * 2 + 1];
    for (int i = threadIdx.x; i < n; i += 256) {
        float v = (p[i] - mu) * rs;
        float y = (i < len) ? (v * g0 + b0) : (v * g1 + b1);
        p[i] = 0.5f * y * (1.f + erff(y * 0.70710678118654752f));
    }
}

// ---------------------------------------------------------------------------
// transpose [B,256,512] -> [B,512,256] and add sinusoidal positional encoding
// grid (16 s-tiles, B), block 256.
__global__ __launch_bounds__(256) void maeeg_transpose_pos_kernel(
    const float* __restrict__ in, float* __restrict__ out)
{
    __shared__ float tile[256][33];
    const int s0 = blockIdx.x * 32, b = blockIdx.y;
    for (int idx = threadIdx.x; idx < 256 * 32; idx += 256) {
        int e = idx >> 5, j = idx & 31;
        tile[e][j] = in[((size_t)b * 256 + e) * 512 + s0 + j];
    }
    __syncthreads();
    for (int idx = threadIdx.x; idx < 32 * 256; idx += 256) {
        int j = idx >> 8, e = idx & 255;
        float s = (float)(s0 + j);
        float ang = s / powf(10000.f, (float)e * (1.f / 256.f));
        float pe = (e & 1) ? cosf(ang) : sinf(ang);
        out[((size_t)b * 512 + s0 + j) * 256 + e] = tile[e][j] + pe;
    }
}

// ---------------------------------------------------------------------------
// attention: one lane = one q row, online softmax over 512 keys, HD=32.
// q,k,v,att all [B,512,256] with head h at column h*32. grid (2,8,32), blk 256.
__global__ __launch_bounds__(256) void maeeg_attn_kernel(
    const float* __restrict__ q, const float* __restrict__ k,
    const float* __restrict__ v, float* __restrict__ att)
{
    const int qt = blockIdx.x, h = blockIdx.y, b = blockIdx.z;
    const int row = qt * 256 + threadIdx.x;
    const float* qp = q + ((size_t)(b * 512 + row)) * 256 + h * 32;
    float4 qr[8];
#pragma unroll
    for (int i = 0; i < 8; ++i) qr[i] = ((const float4*)qp)[i];
    float m = -1e30f, l = 0.f;
    float o[32];
#pragma unroll
    for (int i = 0; i < 32; ++i) o[i] = 0.f;
    const float* kb = k + ((size_t)b * 512) * 256 + h * 32;
    const float* vb = v + ((size_t)b * 512) * 256 + h * 32;
    for (int kk = 0; kk < 512; ++kk) {
        const float4* kp = (const float4*)(kb + (size_t)kk * 256);
        float s = 0.f;
#pragma unroll
        for (int i = 0; i < 8; ++i) {
            float4 kv = kp[i];
            s += qr[i].x * kv.x + qr[i].y * kv.y + qr[i].z * kv.z + qr[i].w * kv.w;
        }
        s *= 0.17677669529663687f;  // 1/sqrt(32)
        if (s > m) {  // rescale running state (exact online softmax)
            float c = __expf(m - s);
            l *= c;
#pragma unroll
            for (int i = 0; i < 32; ++i) o[i] *= c;
            m = s;
        }
        float p = __expf(s - m);
        l += p;
        const float4* vp = (const float4*)(vb + (size_t)kk * 256);
#pragma unroll
        for (int i = 0; i < 8; ++i) {
            float4 vv = vp[i];
            o[4 * i + 0] += p * vv.x; o[4 * i + 1] += p * vv.y;
            o[4 * i + 2] += p * vv.z; o[4 * i + 3] += p * vv.w;
        }
    }
    float inv = 1.f / l;
    float4* op = (float4*)(att + ((size_t)(b * 512 + row)) * 256 + h * 32);
#pragma unroll
    for (int i = 0; i < 8; ++i)
        op[i] = make_float4(o[4 * i] * inv, o[4 * i + 1] * inv,
                            o[4 * i + 2] * inv, o[4 * i + 3] * inv);
}

// ---------------------------------------------------------------------------
// LayerNorm over E=256 (one block per row, in-place safe)
__global__ __launch_bounds__(256) void maeeg_ln_kernel(
    const float* __restrict__ in, float* __restrict__ out,
    const float* __restrict__ g, const float* __restrict__ b)
{
    const int m = blockIdx.x, t = threadIdx.x;
    float x = in[(size_t)m * 256 + t];
    __shared__ float sc[4];
    float mu = maeeg_block_sum(x, sc) * (1.f / 256.f);
    float d = x - mu;
    float var = maeeg_block_sum(d * d, sc) * (1.f / 256.f);
    out[(size_t)m * 256 + t] = d * rsqrtf(var + 1e-5f) * g[t] + b[t];
}

// ---------------------------------------------------------------------------
// classifier stage 1: split-K partials of flat[32,131072] @ Wc1[256,131072]^T
// grid (64 ksplit, 4 jtile), block 256. Wc1 read exactly once from HBM.
__global__ __launch_bounds__(256) void maeeg_cls1_kernel(
    const float* __restrict__ flat, const float* __restrict__ Wc1,
    float* __restrict__ part)
{
    const int ks = blockIdx.x, jt = blockIdx.y, t = threadIdx.x;
    const int jl = t & 63, bg = t >> 6;
    __shared__ float fsh[32][257];
    __shared__ float wsh[64][257];
    float acc[8];
#pragma unroll
    for (int i = 0; i < 8; ++i) acc[i] = 0.f;
    for (int kkc = 0; kkc < 8; ++kkc) {
        int kbase = ks * 2048 + kkc * 256;
        for (int idx = t; idx < 32 * 256; idx += 256) {
            int r = idx >> 8, c = idx & 255;
            fsh[r][c] = flat[(size_t)r * 131072 + kbase + c];
        }
        for (int idx = t; idx < 64 * 256; idx += 256) {
            int r = idx >> 8, c = idx & 255;
            wsh[r][c] = Wc1[(size_t)(jt * 64 + r) * 131072 + kbase + c];
        }
        __syncthreads();
        for (int i = 0; i < 256; ++i) {
            float wv = wsh[jl][i];
#pragma unroll
            for (int bb = 0; bb < 8; ++bb) acc[bb] += wv * fsh[bg * 8 + bb][i];
        }
        __syncthreads();
    }
#pragma unroll
    for (int bb = 0; bb < 8; ++bb)
        part[((size_t)ks * 32 + bg * 8 + bb) * 256 + jt * 64 + jl] = acc[bb];
}

__global__ void maeeg_cls2_kernel(const float* __restrict__ part,
                                  const float* __restrict__ bc1,
                                  float* __restrict__ hid)
{
    const int b = blockIdx.x, j = threadIdx.x;
    float s = bc1[j];
    for (int ks = 0; ks < 64; ++ks) s += part[((size_t)ks * 32 + b) * 256 + j];
    hid[b * 256 + j] = fmaxf(s, 0.f);
}

__global__ void maeeg_cls3_kernel(const float* __restrict__ hid,
                                  const float* __restrict__ Wc2,
                                  const float* __restrict__ bc2,
                                  float* __restrict__ out)
{
    const int b = blockIdx.x, t = threadIdx.x;
    float v = hid[b * 256 + t] * Wc2[t];
#pragma unroll
    for (int off = 32; off; off >>= 1) v += __shfl_down(v, off);
    __shared__ float r[4];
    if ((t & 63) == 0) r[t >> 6] = v;
    __syncthreads();
    if (t == 0) {
        float s = r[0] + r[1] + r[2] + r[3] + bc2[0];
        out[b] = 1.f / (1.f + expf(-s));
    }
}

// ===========================================================================
extern "C" void kernel_launch(void* const* d_in, const int* in_sizes, int n_in,
                              void* d_out, int out_size, void* d_ws, size_t ws_size,
                              hipStream_t stream)
{
    (void)in_sizes; (void)n_in; (void)out_size; (void)ws_size;
    const float* x        = (const float*)d_in[0];
    const float* conv0_w  = (const float*)d_in[1];
    const float* conv0_b  = (const float*)d_in[2];
    const float* conv12_w = (const float*)d_in[3];
    const float* conv12_b = (const float*)d_in[4];
    const float* gn_g     = (const float*)d_in[5];
    const float* gn_b     = (const float*)d_in[6];
    const float* Wq       = (const float*)d_in[7];
    const float* Wk       = (const float*)d_in[8];
    const float* Wv       = (const float*)d_in[9];
    const float* Wo       = (const float*)d_in[10];
    const float* ln1_g    = (const float*)d_in[11];
    const float* ln1_b    = (const float*)d_in[12];
    const float* Wf1      = (const float*)d_in[13];
    const float* bf1      = (const float*)d_in[14];
    const float* Wf2      = (const float*)d_in[15];
    const float* bf2      = (const float*)d_in[16];
    const float* ln2_g    = (const float*)d_in[17];
    const float* ln2_b    = (const float*)d_in[18];
    const float* Wc1      = (const float*)d_in[19];
    const float* bc1      = (const float*)d_in[20];
    const float* Wc2      = (const float*)d_in[21];
    const float* bc2      = (const float*)d_in[22];
    float* out = (float*)d_out;

    // workspace layout (floats)
    float* ws   = (float*)d_ws;
    float* A    = ws;                  // 16,777,216  (conv0 out / q,k,v,att / f1)
    float* Bb   = A + 16777216;        //  8,388,608  (conv1 out)
    float* C    = Bb + 8388608;        //  4,194,304  (h)
    float* D    = C + 4194304;         //  4,194,304  (conv2 out / r1 / h1n)
    float* PART = D + 4194304;         //    524,288
    float* HID  = PART + 524288;       //      8,192

    float* Q   = A;
    float* Kb  = A + 4194304;
    float* Vb  = A + 8388608;
    float* ATT = A + 12582912;
    float* F1  = A;  // reuses q/k/v/att after attention+Wo are done

    // ---- conv encoder ----
    maeeg_conv_kernel<<<dim3(2, 16, 32), 256, 0, stream>>>(
        x, conv0_w, conv0_b, A, 64, 4096, 2048);
    maeeg_gn_gelu_kernel<<<dim3(128, 32), 256, 0, stream>>>(A, gn_g, gn_b, 2048);
    maeeg_conv_kernel<<<dim3(2, 8, 32), 256, 0, stream>>>(
        A, conv12_w, conv12_b, Bb, 256, 2048, 1024);
    maeeg_gn_gelu_kernel<<<dim3(128, 32), 256, 0, stream>>>(
        Bb, gn_g + 256, gn_b + 256, 1024);
    maeeg_conv_kernel<<<dim3(2, 4, 32), 256, 0, stream>>>(
        Bb, conv12_w + 983040, conv12_b + 256, D, 256, 1024, 512);
    maeeg_gn_gelu_kernel<<<dim3(128, 32), 256, 0, stream>>>(
        D, gn_g + 512, gn_b + 512, 512);
    maeeg_transpose_pos_kernel<<<dim3(16, 32), 256, 0, stream>>>(D, C);

    // ---- transformer encoder ----
    for (int l = 0; l < 4; ++l) {
        maeeg_fc_kernel<<<dim3(128, 2), 256, 0, stream>>>(
            C, Wq + l * 65536, nullptr, nullptr, Q, 256, 256, 0);
        maeeg_fc_kernel<<<dim3(128, 2), 256, 0, stream>>>(
            C, Wk + l * 65536, nullptr, nullptr, Kb, 256, 256, 0);
        maeeg_fc_kernel<<<dim3(128, 2), 256, 0, stream>>>(
            C, Wv + l * 65536, nullptr, nullptr, Vb, 256, 256, 0);
        maeeg_attn_kernel<<<dim3(2, 8, 32), 256, 0, stream>>>(Q, Kb, Vb, ATT);
        maeeg_fc_kernel<<<dim3(128, 2), 256, 0, stream>>>(
            ATT, Wo + l * 65536, nullptr, C, D, 256, 256, 0);
        maeeg_ln_kernel<<<dim3(16384), 256, 0, stream>>>(
            D, D, ln1_g + l * 256, ln1_b + l * 256);
        maeeg_fc_kernel<<<dim3(128, 8), 256, 0, stream>>>(
            D, Wf1 + l * 262144, bf1 + l * 1024, nullptr, F1, 1024, 256, 1);
        maeeg_fc_kernel<<<dim3(128, 2), 256, 0, stream>>>(
            F1, Wf2 + l * 262144, bf2 + l * 256, D, C, 256, 1024, 0);
        maeeg_ln_kernel<<<dim3(16384), 256, 0, stream>>>(
            C, C, ln2_g + l * 256, ln2_b + l * 256);
    }

    // ---- classifier ----
    maeeg_cls1_kernel<<<dim3(64, 4), 256, 0, stream>>>(C, Wc1, PART);
    maeeg_cls2_kernel<<<dim3(32), 256, 0, stream>>>(PART, bc1, HID);
    maeeg_cls3_kernel<<<dim3(32), 256, 0, stream>>>(HID, Wc2, bc2, out);
}

// Round 2
// 4036.025 us; speedup vs baseline: 1.5886x; 1.5886x over previous
//
#include <hip/hip_runtime.h>
#include <math.h>

// ============================================================================
// MAEEG classification, round 2: bf16 MFMA for all GEMM-shaped work.
//   - mm kernel: 128x128x64 tile, 4 waves x (4x4 16x16x32 frags), fp32 accum.
//     Reg-staged LDS with XOR swizzle (chunk ^= row&7) on write AND read
//     -> 2-way-max bank aliasing on ds_read_b128 (free per CDNA4).
//   - convs: implicit GEMM. K padded CINx15 -> CINx16 (zero weight col) so
//     8-elem fragments never cross channel rows; input bf16 shadow is
//     7-zero-padded per channel row so stride-2 gathers need no predication.
//   - fp32 master activation path (GN/LN/residual/classifier); bf16 shadows
//     written fused in GN/LN/transpose epilogues.
//   - attention stays fp32 vector (online softmax), now emits bf16 for Wo.
// ws layout (131.1 MB): WB 11 | R1 17 (xpad/gn1b/D) | R2 67.1 (conv0/qkvatt/f1)
//                       | R3 33.8 (gn0b / C+Cb) | R4 2.1 (part/hid)
// ============================================================================

typedef unsigned int   u32;
typedef unsigned short u16;
typedef __attribute__((ext_vector_type(4))) float f32x4;
typedef __attribute__((ext_vector_type(8))) short bf16x8;

__device__ __forceinline__ u16 f2bf(float v) {
    union { float f; u32 u; } x; x.f = v;
    u32 r = x.u + 0x7fffu + ((x.u >> 16) & 1u);  // RNE
    return (u16)(r >> 16);
}

// ---------------------------------------------------------------------------
// block-wide sum over 256 threads (4 waves)
__device__ __forceinline__ float maeeg_block_sum(float v, float* sc4) {
#pragma unroll
    for (int off = 32; off; off >>= 1) v += __shfl_down(v, off);
    int t = threadIdx.x;
    if ((t & 63) == 0) sc4[t >> 6] = v;
    __syncthreads();
    float r = sc4[0] + sc4[1] + sc4[2] + sc4[3];
    __syncthreads();
    return r;
}

// ---------------------------------------------------------------------------
// bf16 MFMA GEMM: out[m][n] = sum_k A[m][k]*B[n][k] (+bias[n]) (+res) (relu)
// A:[M][K] bf16, B:[N][K] bf16 (both K-major). M,N %128==0, K %64==0.
// flags: 1 = relu, 2 = bf16 output (else fp32). grid (M/128, N/128), 256 thr.
__global__ __launch_bounds__(256) void maeeg_mm_kernel(
    const u16* __restrict__ Ag, const u16* __restrict__ Bg,
    const float* __restrict__ bias, const float* __restrict__ res,
    void* __restrict__ outp, int N, int K, int flags)
{
    __shared__ u16 As[8192];  // [128 rows][64 k] bf16, 128B/row, XOR-swizzled
    __shared__ u16 Bs[8192];
    const int m0 = blockIdx.x * 128, n0 = blockIdx.y * 128;
    const int t = threadIdx.x, w = t >> 6, lane = t & 63;
    const int sr = lane & 7, sc = lane >> 3;    // stage: row-in-group, chunk
    const int fr = lane & 15, fq = lane >> 4;   // frag: row, k-quarter
    const int wm = (w >> 1) * 64, wn = (w & 1) * 64;

    f32x4 acc[4][4];
    const f32x4 zero = {0.f, 0.f, 0.f, 0.f};
#pragma unroll
    for (int i = 0; i < 4; ++i)
#pragma unroll
        for (int j = 0; j < 4; ++j) acc[i][j] = zero;

    for (int k0 = 0; k0 < K; k0 += 64) {
#pragma unroll
        for (int j = 0; j < 4; ++j) {
            int row = w * 32 + j * 8 + sr;
            uint4 va = *(const uint4*)(Ag + (size_t)(m0 + row) * K + k0 + sc * 8);
            uint4 vb = *(const uint4*)(Bg + (size_t)(n0 + row) * K + k0 + sc * 8);
            int kb = (sc ^ (row & 7)) << 4;     // swizzled byte offset in row
            *(uint4*)((char*)As + row * 128 + kb) = va;
            *(uint4*)((char*)Bs + row * 128 + kb) = vb;
        }
        __syncthreads();
#pragma unroll
        for (int kc = 0; kc < 2; ++kc) {
            bf16x8 af[4], bfv[4];
#pragma unroll
            for (int i = 0; i < 4; ++i) {
                int am = wm + i * 16 + fr;
                int bn = wn + i * 16 + fr;
                int kb = kc * 64 + fq * 16;
                af[i]  = *(const bf16x8*)((const char*)As + am * 128 + (kb ^ ((am & 7) << 4)));
                bfv[i] = *(const bf16x8*)((const char*)Bs + bn * 128 + (kb ^ ((bn & 7) << 4)));
            }
#pragma unroll
            for (int i = 0; i < 4; ++i)
#pragma unroll
                for (int j = 0; j < 4; ++j)
                    acc[i][j] = __builtin_amdgcn_mfma_f32_16x16x32_bf16(
                        af[i], bfv[j], acc[i][j], 0, 0, 0);
        }
        __syncthreads();
    }
    // epilogue: D row = (lane>>4)*4+reg (A/m side), col = lane&15 (B/n side)
#pragma unroll
    for (int i = 0; i < 4; ++i) {
#pragma unroll
        for (int j = 0; j < 4; ++j) {
            int n = n0 + wn + j * 16 + fr;
            float bv = bias ? bias[n] : 0.f;
#pragma unroll
            for (int r = 0; r < 4; ++r) {
                int m = m0 + wm + i * 16 + fq * 4 + r;
                float v = acc[i][j][r] + bv;
                if (res) v += res[(size_t)m * N + n];
                if (flags & 1) v = fmaxf(v, 0.f);
                if (flags & 2) ((u16*)outp)[(size_t)m * N + n] = f2bf(v);
                else           ((float*)outp)[(size_t)m * N + n] = v;
            }
        }
    }
}

// ---------------------------------------------------------------------------
// bf16 MFMA implicit-GEMM conv1d (stride 2, taps 15 padded to 16).
// Wp:[256][K3] bf16 (K3=CIN*16, tap 15 zeroed). inp:[B][CIN][len_in+16] bf16,
// 7 leading zeros per row: B[t][ci*16+r] = inp[ci][2t + r].
// out fp32 [B][256][len_out]. grid (2, len_out/128, B), 256 thr.
__global__ __launch_bounds__(256) void maeeg_convmm_kernel(
    const u16* __restrict__ Wp, const u16* __restrict__ inp,
    const float* __restrict__ cb, float* __restrict__ out,
    int K3, int len_in, int len_out)
{
    __shared__ u16 As[8192];
    __shared__ u16 Bs[8192];
    const int m0 = blockIdx.x * 128, t0 = blockIdx.y * 128, b = blockIdx.z;
    const int lip = len_in + 16;
    const u16* inb = inp + (size_t)b * (K3 >> 4) * lip;
    const int t = threadIdx.x, w = t >> 6, lane = t & 63;
    const int sr = lane & 7, sc = lane >> 3;
    const int fr = lane & 15, fq = lane >> 4;
    const int wm = (w >> 1) * 64, wn = (w & 1) * 64;

    f32x4 acc[4][4];
    const f32x4 zero = {0.f, 0.f, 0.f, 0.f};
#pragma unroll
    for (int i = 0; i < 4; ++i)
#pragma unroll
        for (int j = 0; j < 4; ++j) acc[i][j] = zero;

    for (int k0 = 0; k0 < K3; k0 += 64) {
#pragma unroll
        for (int j = 0; j < 4; ++j) {
            int row = w * 32 + j * 8 + sr;
            // A: weight rows, contiguous 16B
            uint4 va = *(const uint4*)(Wp + (size_t)(m0 + row) * K3 + k0 + sc * 8);
            // B: gathered input, 4B-aligned (element offset even) -> 4 dwords
            int k  = k0 + sc * 8;
            int ci = k >> 4, rr = k & 15;           // rr in {0,8}
            int tg = t0 + row;
            const u16* gp = inb + (size_t)ci * lip + 2 * tg + rr;
            uint4 vb;
            vb.x = *(const u32*)(gp);
            vb.y = *(const u32*)(gp + 2);
            vb.z = *(const u32*)(gp + 4);
            vb.w = *(const u32*)(gp + 6);
            int kb = (sc ^ (row & 7)) << 4;
            *(uint4*)((char*)As + row * 128 + kb) = va;
            *(uint4*)((char*)Bs + row * 128 + kb) = vb;
        }
        __syncthreads();
#pragma unroll
        for (int kc = 0; kc < 2; ++kc) {
            bf16x8 af[4], bfv[4];
#pragma unroll
            for (int i = 0; i < 4; ++i) {
                int am = wm + i * 16 + fr;
                int bn = wn + i * 16 + fr;
                int kb = kc * 64 + fq * 16;
                af[i]  = *(const bf16x8*)((const char*)As + am * 128 + (kb ^ ((am & 7) << 4)));
                bfv[i] = *(const bf16x8*)((const char*)Bs + bn * 128 + (kb ^ ((bn & 7) << 4)));
            }
#pragma unroll
            for (int i = 0; i < 4; ++i)
#pragma unroll
                for (int j = 0; j < 4; ++j)
                    acc[i][j] = __builtin_amdgcn_mfma_f32_16x16x32_bf16(
                        af[i], bfv[j], acc[i][j], 0, 0, 0);
        }
        __syncthreads();
    }
#pragma unroll
    for (int i = 0; i < 4; ++i) {
#pragma unroll
        for (int r = 0; r < 4; ++r) {
            int m = m0 + wm + i * 16 + fq * 4 + r;
            float bb = cb[m];
            float* op = out + ((size_t)b * 256 + m) * len_out + t0;
#pragma unroll
            for (int j = 0; j < 4; ++j)
                op[wn + j * 16 + fr] = acc[i][j][r] + bb;
        }
    }
}

// ---------------------------------------------------------------------------
// weight prep: fp32 [O][CIN][15] -> bf16 [O][CIN*16] (tap 15 = 0)
__global__ void maeeg_prep_convw_kernel(const float* __restrict__ src,
                                        u16* __restrict__ dst, int n)
{
    int i = blockIdx.x * 256 + threadIdx.x;
    if (i >= n) return;
    int r = i & 15, base = i >> 4;
    dst[i] = (r < 15) ? f2bf(src[(size_t)base * 15 + r]) : (u16)0;
}

__global__ void maeeg_cast_kernel(const float* __restrict__ src,
                                  u16* __restrict__ dst, int n)
{
    int i = blockIdx.x * 256 + threadIdx.x;
    if (i < n) dst[i] = f2bf(src[i]);
}

// fp32 [rows][len] -> bf16 [rows][len+16], 7 leading zeros per row
__global__ void maeeg_cast_pad_kernel(const float* __restrict__ src,
                                      u16* __restrict__ dst, int len)
{
    int lip = len + 16;
    int p = blockIdx.x * 256 + threadIdx.x;
    int row = blockIdx.y;
    if (p >= lip) return;
    int q = p - 7;
    dst[(size_t)row * lip + p] =
        (q >= 0 && q < len) ? f2bf(src[(size_t)row * len + q]) : (u16)0;
}

// ---------------------------------------------------------------------------
// GroupNorm (2 ch/group) + exact GELU, in place; optional padded bf16 shadow.
// grid (128, B), block 256.
__global__ __launch_bounds__(256) void maeeg_gn_gelu_kernel(
    float* __restrict__ h, const float* __restrict__ g,
    const float* __restrict__ bta, int len, u16* __restrict__ bfout, int lip)
{
    const int grp = blockIdx.x, b = blockIdx.y;
    float* p = h + ((size_t)b * 256 + grp * 2) * len;
    const int n = 2 * len;
    float s1 = 0.f, s2 = 0.f;
    for (int i = threadIdx.x; i < n; i += 256) {
        float v = p[i];
        s1 += v; s2 += v * v;
    }
    __shared__ float sc[4];
    float S1 = maeeg_block_sum(s1, sc);
    float S2 = maeeg_block_sum(s2, sc);
    float mu = S1 / (float)n;
    float var = fmaxf(S2 / (float)n - mu * mu, 0.f);
    float rs = rsqrtf(var + 1e-5f);
    float g0 = g[grp * 2], g1 = g[grp * 2 + 1];
    float b0 = bta[grp * 2], b1 = bta[grp * 2 + 1];
    u16* bp = bfout ? bfout + ((size_t)b * 256 + grp * 2) * lip : (u16*)0;
    for (int i = threadIdx.x; i < n; i += 256) {
        float v = (p[i] - mu) * rs;
        float y = (i < len) ? (v * g0 + b0) : (v * g1 + b1);
        float ge = 0.5f * y * (1.f + erff(y * 0.70710678118654752f));
        p[i] = ge;
        if (bp) bp[(i < len ? i : (i - len) + lip) + 7] = f2bf(ge);
    }
    if (bp && threadIdx.x < 32) {  // zero the pads (ws is 0xAA-poisoned)
        int ch = threadIdx.x >> 4, pp = threadIdx.x & 15;
        bp[(size_t)ch * lip + ((pp < 7) ? pp : (len + pp))] = 0;
    }
}

// ---------------------------------------------------------------------------
// transpose [B,256,512] -> [B,512,256], add sinusoidal pos enc; fp32 + bf16.
__global__ __launch_bounds__(256) void maeeg_transpose_pos_kernel(
    const float* __restrict__ in, float* __restrict__ out,
    u16* __restrict__ outb)
{
    __shared__ float tile[256][33];
    const int s0 = blockIdx.x * 32, b = blockIdx.y;
    for (int idx = threadIdx.x; idx < 256 * 32; idx += 256) {
        int e = idx >> 5, j = idx & 31;
        tile[e][j] = in[((size_t)b * 256 + e) * 512 + s0 + j];
    }
    __syncthreads();
    for (int idx = threadIdx.x; idx < 32 * 256; idx += 256) {
        int j = idx >> 8, e = idx & 255;
        float s = (float)(s0 + j);
        float ang = s / powf(10000.f, (float)e * (1.f / 256.f));
        float pe = (e & 1) ? cosf(ang) : sinf(ang);
        float v = tile[e][j] + pe;
        size_t o = ((size_t)b * 512 + s0 + j) * 256 + e;
        out[o] = v;
        outb[o] = f2bf(v);
    }
}

// ---------------------------------------------------------------------------
// attention: lane = one q row, online softmax over 512 keys, HD=32.
// q,k,v fp32 [B,512,256] (head at col h*32); att out bf16. grid (2,8,B).
__global__ __launch_bounds__(256) void maeeg_attn_kernel(
    const float* __restrict__ q, const float* __restrict__ k,
    const float* __restrict__ v, u16* __restrict__ att)
{
    const int qt = blockIdx.x, h = blockIdx.y, b = blockIdx.z;
    const int row = qt * 256 + threadIdx.x;
    const float* qp = q + ((size_t)(b * 512 + row)) * 256 + h * 32;
    float4 qr[8];
#pragma unroll
    for (int i = 0; i < 8; ++i) qr[i] = ((const float4*)qp)[i];
    float m = -1e30f, l = 0.f;
    float o[32];
#pragma unroll
    for (int i = 0; i < 32; ++i) o[i] = 0.f;
    const float* kb = k + ((size_t)b * 512) * 256 + h * 32;
    const float* vb = v + ((size_t)b * 512) * 256 + h * 32;
    for (int kk = 0; kk < 512; ++kk) {
        const float4* kp = (const float4*)(kb + (size_t)kk * 256);
        float s = 0.f;
#pragma unroll
        for (int i = 0; i < 8; ++i) {
            float4 kv = kp[i];
            s += qr[i].x * kv.x + qr[i].y * kv.y + qr[i].z * kv.z + qr[i].w * kv.w;
        }
        s *= 0.17677669529663687f;  // 1/sqrt(32)
        if (s > m) {
            float c = __expf(m - s);
            l *= c;
#pragma unroll
            for (int i = 0; i < 32; ++i) o[i] *= c;
            m = s;
        }
        float p = __expf(s - m);
        l += p;
        const float4* vp = (const float4*)(vb + (size_t)kk * 256);
#pragma unroll
        for (int i = 0; i < 8; ++i) {
            float4 vv = vp[i];
            o[4 * i + 0] += p * vv.x; o[4 * i + 1] += p * vv.y;
            o[4 * i + 2] += p * vv.z; o[4 * i + 3] += p * vv.w;
        }
    }
    float inv = 1.f / l;
    u32* op = (u32*)(att + ((size_t)(b * 512 + row)) * 256 + h * 32);
#pragma unroll
    for (int i = 0; i < 16; ++i)
        op[i] = (u32)f2bf(o[2 * i] * inv) | ((u32)f2bf(o[2 * i + 1] * inv) << 16);
}

// ---------------------------------------------------------------------------
// LayerNorm over E=256 + bf16 shadow (one block per row)
__global__ __launch_bounds__(256) void maeeg_ln_kernel(
    const float* __restrict__ in, float* __restrict__ out,
    u16* __restrict__ bfout, const float* __restrict__ g,
    const float* __restrict__ b)
{
    const int m = blockIdx.x, t = threadIdx.x;
    float x = in[(size_t)m * 256 + t];
    __shared__ float sc[4];
    float mu = maeeg_block_sum(x, sc) * (1.f / 256.f);
    float d = x - mu;
    float var = maeeg_block_sum(d * d, sc) * (1.f / 256.f);
    float v = d * rsqrtf(var + 1e-5f) * g[t] + b[t];
    out[(size_t)m * 256 + t] = v;
    bfout[(size_t)m * 256 + t] = f2bf(v);
}

// ---------------------------------------------------------------------------
// classifier (fp32, Wc1 read once from HBM)
__global__ __launch_bounds__(256) void maeeg_cls1_kernel(
    const float* __restrict__ flat, const float* __restrict__ Wc1,
    float* __restrict__ part)
{
    const int ks = blockIdx.x, jt = blockIdx.y, t = threadIdx.x;
    const int jl = t & 63, bg = t >> 6;
    __shared__ float fsh[32][257];
    __shared__ float wsh[64][257];
    float acc[8];
#pragma unroll
    for (int i = 0; i < 8; ++i) acc[i] = 0.f;
    for (int kkc = 0; kkc < 8; ++kkc) {
        int kbase = ks * 2048 + kkc * 256;
        for (int idx = t; idx < 32 * 256; idx += 256) {
            int r = idx >> 8, c = idx & 255;
            fsh[r][c] = flat[(size_t)r * 131072 + kbase + c];
        }
        for (int idx = t; idx < 64 * 256; idx += 256) {
            int r = idx >> 8, c = idx & 255;
            wsh[r][c] = Wc1[(size_t)(jt * 64 + r) * 131072 + kbase + c];
        }
        __syncthreads();
        for (int i = 0; i < 256; ++i) {
            float wv = wsh[jl][i];
#pragma unroll
            for (int bb = 0; bb < 8; ++bb) acc[bb] += wv * fsh[bg * 8 + bb][i];
        }
        __syncthreads();
    }
#pragma unroll
    for (int bb = 0; bb < 8; ++bb)
        part[((size_t)ks * 32 + bg * 8 + bb) * 256 + jt * 64 + jl] = acc[bb];
}

__global__ void maeeg_cls2_kernel(const float* __restrict__ part,
                                  const float* __restrict__ bc1,
                                  float* __restrict__ hid)
{
    const int b = blockIdx.x, j = threadIdx.x;
    float s = bc1[j];
    for (int ks = 0; ks < 64; ++ks) s += part[((size_t)ks * 32 + b) * 256 + j];
    hid[b * 256 + j] = fmaxf(s, 0.f);
}

__global__ void maeeg_cls3_kernel(const float* __restrict__ hid,
                                  const float* __restrict__ Wc2,
                                  const float* __restrict__ bc2,
                                  float* __restrict__ out)
{
    const int b = blockIdx.x, t = threadIdx.x;
    float v = hid[b * 256 + t] * Wc2[t];
#pragma unroll
    for (int off = 32; off; off >>= 1) v += __shfl_down(v, off);
    __shared__ float r[4];
    if ((t & 63) == 0) r[t >> 6] = v;
    __syncthreads();
    if (t == 0) {
        float s = r[0] + r[1] + r[2] + r[3] + bc2[0];
        out[b] = 1.f / (1.f + expf(-s));
    }
}

// ===========================================================================
extern "C" void kernel_launch(void* const* d_in, const int* in_sizes, int n_in,
                              void* d_out, int out_size, void* d_ws, size_t ws_size,
                              hipStream_t stream)
{
    (void)in_sizes; (void)n_in; (void)out_size; (void)ws_size;
    const float* x        = (const float*)d_in[0];
    const float* conv0_w  = (const float*)d_in[1];
    const float* conv0_b  = (const float*)d_in[2];
    const float* conv12_w = (const float*)d_in[3];
    const float* conv12_b = (const float*)d_in[4];
    const float* gn_g     = (const float*)d_in[5];
    const float* gn_b     = (const float*)d_in[6];
    const float* Wq       = (const float*)d_in[7];
    const float* Wk       = (const float*)d_in[8];
    const float* Wv       = (const float*)d_in[9];
    const float* Wo       = (const float*)d_in[10];
    const float* ln1_g    = (const float*)d_in[11];
    const float* ln1_b    = (const float*)d_in[12];
    const float* Wf1      = (const float*)d_in[13];
    const float* bf1      = (const float*)d_in[14];
    const float* Wf2      = (const float*)d_in[15];
    const float* bf2      = (const float*)d_in[16];
    const float* ln2_g    = (const float*)d_in[17];
    const float* ln2_b    = (const float*)d_in[18];
    const float* Wc1      = (const float*)d_in[19];
    const float* bc1      = (const float*)d_in[20];
    const float* Wc2      = (const float*)d_in[21];
    const float* bc2      = (const float*)d_in[22];
    float* out = (float*)d_out;

    // ---- workspace layout (bytes, all 256-aligned) ----
    char* wsb = (char*)d_ws;
    u16* WB0   = (u16*)(wsb + 0);          // 256*1024*2      = 524288
    u16* WB12  = (u16*)(wsb + 524288);     // 2*256*4096*2    = 4194304
    u16* WQb   = (u16*)(wsb + 4718592);    // 262144*2
    u16* WKb   = (u16*)(wsb + 5242880);
    u16* WVb   = (u16*)(wsb + 5767168);
    u16* WOb   = (u16*)(wsb + 6291456);
    u16* WF1b  = (u16*)(wsb + 6815744);    // 1048576*2
    u16* WF2b  = (u16*)(wsb + 8912896);    // 1048576*2 -> end 11010048
    // R1 (17,039,360 B): XPAD -> GN1B -> D
    u16*   XPAD  = (u16*)(wsb + 11010048);   // 32*64*4112*2 = 16842752
    u16*   GN1B  = (u16*)(wsb + 11010048);   // 32*256*1040*2 = 17039360
    float* D     = (float*)(wsb + 11010048); // 16777216
    // R2 (67,108,864 B): CONV0 -> CONV1+CONV2 -> Qf/Kf/Vf/ATTb+Db -> F1b
    float* CONV0 = (float*)(wsb + 28049408);
    float* CONV1 = (float*)(wsb + 28049408);
    float* CONV2 = (float*)(wsb + 28049408 + 33554432);
    float* Qf    = (float*)(wsb + 28049408);
    float* Kf    = (float*)(wsb + 28049408 + 16777216);
    float* Vf    = (float*)(wsb + 28049408 + 33554432);
    u16*   ATTb  = (u16*)(wsb + 28049408 + 50331648);
    u16*   Db    = (u16*)(wsb + 28049408 + 58720256);
    u16*   F1b   = (u16*)(wsb + 28049408);   // 16384*1024*2 = 33554432
    // R3 (33,816,576 B): GN0B -> C + Cb
    u16*   GN0B  = (u16*)(wsb + 95158272);   // 32*256*2064*2
    float* C     = (float*)(wsb + 95158272);
    u16*   Cb    = (u16*)(wsb + 95158272 + 16777216);
    // R4
    float* PART  = (float*)(wsb + 128974848);
    float* HID   = (float*)(wsb + 128974848 + 2097152);

    // ---- weight prep (bf16 shadows) ----
    maeeg_prep_convw_kernel<<<1024, 256, 0, stream>>>(conv0_w, WB0, 262144);
    maeeg_prep_convw_kernel<<<8192, 256, 0, stream>>>(conv12_w, WB12, 2097152);
    maeeg_cast_kernel<<<1024, 256, 0, stream>>>(Wq, WQb, 262144);
    maeeg_cast_kernel<<<1024, 256, 0, stream>>>(Wk, WKb, 262144);
    maeeg_cast_kernel<<<1024, 256, 0, stream>>>(Wv, WVb, 262144);
    maeeg_cast_kernel<<<1024, 256, 0, stream>>>(Wo, WOb, 262144);
    maeeg_cast_kernel<<<4096, 256, 0, stream>>>(Wf1, WF1b, 1048576);
    maeeg_cast_kernel<<<4096, 256, 0, stream>>>(Wf2, WF2b, 1048576);
    maeeg_cast_pad_kernel<<<dim3(17, 2048), 256, 0, stream>>>(x, XPAD, 4096);

    // ---- conv encoder ----
    maeeg_convmm_kernel<<<dim3(2, 16, 32), 256, 0, stream>>>(
        WB0, XPAD, conv0_b, CONV0, 1024, 4096, 2048);
    maeeg_gn_gelu_kernel<<<dim3(128, 32), 256, 0, stream>>>(
        CONV0, gn_g, gn_b, 2048, GN0B, 2064);
    maeeg_convmm_kernel<<<dim3(2, 8, 32), 256, 0, stream>>>(
        WB12, GN0B, conv12_b, CONV1, 4096, 2048, 1024);
    maeeg_gn_gelu_kernel<<<dim3(128, 32), 256, 0, stream>>>(
        CONV1, gn_g + 256, gn_b + 256, 1024, GN1B, 1040);
    maeeg_convmm_kernel<<<dim3(2, 4, 32), 256, 0, stream>>>(
        WB12 + 256 * 4096, GN1B, conv12_b + 256, CONV2, 4096, 1024, 512);
    maeeg_gn_gelu_kernel<<<dim3(128, 32), 256, 0, stream>>>(
        CONV2, gn_g + 512, gn_b + 512, 512, (u16*)0, 0);
    maeeg_transpose_pos_kernel<<<dim3(16, 32), 256, 0, stream>>>(CONV2, C, Cb);

    // ---- transformer encoder ----
    for (int l = 0; l < 4; ++l) {
        maeeg_mm_kernel<<<dim3(128, 2), 256, 0, stream>>>(
            Cb, WQb + l * 65536, (const float*)0, (const float*)0, Qf, 256, 256, 0);
        maeeg_mm_kernel<<<dim3(128, 2), 256, 0, stream>>>(
            Cb, WKb + l * 65536, (const float*)0, (const float*)0, Kf, 256, 256, 0);
        maeeg_mm_kernel<<<dim3(128, 2), 256, 0, stream>>>(
            Cb, WVb + l * 65536, (const float*)0, (const float*)0, Vf, 256, 256, 0);
        maeeg_attn_kernel<<<dim3(2, 8, 32), 256, 0, stream>>>(Qf, Kf, Vf, ATTb);
        maeeg_mm_kernel<<<dim3(128, 2), 256, 0, stream>>>(
            ATTb, WOb + l * 65536, (const float*)0, C, D, 256, 256, 0);
        maeeg_ln_kernel<<<16384, 256, 0, stream>>>(
            D, D, Db, ln1_g + l * 256, ln1_b + l * 256);
        maeeg_mm_kernel<<<dim3(128, 8), 256, 0, stream>>>(
            Db, WF1b + l * 262144, bf1 + l * 1024, (const float*)0, F1b, 1024, 256, 3);
        maeeg_mm_kernel<<<dim3(128, 2), 256, 0, stream>>>(
            F1b, WF2b + l * 262144, bf2 + l * 256, D, C, 256, 1024, 0);
        maeeg_ln_kernel<<<16384, 256, 0, stream>>>(
            C, C, Cb, ln2_g + l * 256, ln2_b + l * 256);
    }

    // ---- classifier ----
    maeeg_cls1_kernel<<<dim3(64, 4), 256, 0, stream>>>(C, Wc1, PART);
    maeeg_cls2_kernel<<<32, 256, 0, stream>>>(PART, bc1, HID);
    maeeg_cls3_kernel<<<32, 256, 0, stream>>>(HID, Wc2, bc2, out);
}

// Round 3
// 1471.413 us; speedup vs baseline: 4.3573x; 2.7430x over previous
//
#include <hip/hip_runtime.h>
#include <math.h>

// ============================================================================
// MAEEG classification, round 3: MFMA flash attention.
//   - mm kernel (unchanged core): 128x128x64 bf16 MFMA tile; epilogue flags:
//     1=relu, 2=bf16 out, 4=transposed bf16 out (Vt[b][n][s]), 8=pre-scale
//     by 1/sqrt(32) (folded into Q projection).
//   - fattn: per block (qt,h,b): 4 waves x 32 q rows; Q frags in registers;
//     per 64-key tile: K/Vt staged in XOR-swizzled LDS, QK^T 8 MFMA,
//     in-register online softmax (shfl_xor row reduce), P -> wave-private
//     swizzled LDS -> PV A-frags, PV 8 MFMA, fp32 accum; final 1/l scale.
//   - everything else as round 2 (convs implicit-GEMM MFMA, fp32 master path).
// ============================================================================

typedef unsigned int   u32;
typedef unsigned short u16;
typedef __attribute__((ext_vector_type(4))) float f32x4;
typedef __attribute__((ext_vector_type(8))) short bf16x8;

__device__ __forceinline__ u16 f2bf(float v) {
    union { float f; u32 u; } x; x.f = v;
    u32 r = x.u + 0x7fffu + ((x.u >> 16) & 1u);  // RNE
    return (u16)(r >> 16);
}

// ---------------------------------------------------------------------------
// block-wide sum over 256 threads (4 waves)
__device__ __forceinline__ float maeeg_block_sum(float v, float* sc4) {
#pragma unroll
    for (int off = 32; off; off >>= 1) v += __shfl_down(v, off);
    int t = threadIdx.x;
    if ((t & 63) == 0) sc4[t >> 6] = v;
    __syncthreads();
    float r = sc4[0] + sc4[1] + sc4[2] + sc4[3];
    __syncthreads();
    return r;
}

// ---------------------------------------------------------------------------
// bf16 MFMA GEMM: out[m][n] = sum_k A[m][k]*B[n][k] (+bias[n]) (+res)
// flags: 1 relu | 2 bf16 out | 4 transposed bf16 out Vt[m>>9][n][m&511] | 8 scale
__global__ __launch_bounds__(256) void maeeg_mm_kernel(
    const u16* __restrict__ Ag, const u16* __restrict__ Bg,
    const float* __restrict__ bias, const float* __restrict__ res,
    void* __restrict__ outp, int N, int K, int flags)
{
    __shared__ u16 As[8192];  // [128 rows][64 k] bf16, 128B/row, XOR-swizzled
    __shared__ u16 Bs[8192];
    const int m0 = blockIdx.x * 128, n0 = blockIdx.y * 128;
    const int t = threadIdx.x, w = t >> 6, lane = t & 63;
    const int sr = lane & 7, sc = lane >> 3;
    const int fr = lane & 15, fq = lane >> 4;
    const int wm = (w >> 1) * 64, wn = (w & 1) * 64;

    f32x4 acc[4][4];
    const f32x4 zero = {0.f, 0.f, 0.f, 0.f};
#pragma unroll
    for (int i = 0; i < 4; ++i)
#pragma unroll
        for (int j = 0; j < 4; ++j) acc[i][j] = zero;

    for (int k0 = 0; k0 < K; k0 += 64) {
#pragma unroll
        for (int j = 0; j < 4; ++j) {
            int row = w * 32 + j * 8 + sr;
            uint4 va = *(const uint4*)(Ag + (size_t)(m0 + row) * K + k0 + sc * 8);
            uint4 vb = *(const uint4*)(Bg + (size_t)(n0 + row) * K + k0 + sc * 8);
            int kb = (sc ^ (row & 7)) << 4;
            *(uint4*)((char*)As + row * 128 + kb) = va;
            *(uint4*)((char*)Bs + row * 128 + kb) = vb;
        }
        __syncthreads();
#pragma unroll
        for (int kc = 0; kc < 2; ++kc) {
            bf16x8 af[4], bfv[4];
#pragma unroll
            for (int i = 0; i < 4; ++i) {
                int am = wm + i * 16 + fr;
                int bn = wn + i * 16 + fr;
                int kb = kc * 64 + fq * 16;
                af[i]  = *(const bf16x8*)((const char*)As + am * 128 + (kb ^ ((am & 7) << 4)));
                bfv[i] = *(const bf16x8*)((const char*)Bs + bn * 128 + (kb ^ ((bn & 7) << 4)));
            }
#pragma unroll
            for (int i = 0; i < 4; ++i)
#pragma unroll
                for (int j = 0; j < 4; ++j)
                    acc[i][j] = __builtin_amdgcn_mfma_f32_16x16x32_bf16(
                        af[i], bfv[j], acc[i][j], 0, 0, 0);
        }
        __syncthreads();
    }
#pragma unroll
    for (int i = 0; i < 4; ++i) {
#pragma unroll
        for (int j = 0; j < 4; ++j) {
            int n = n0 + wn + j * 16 + fr;
            float bv = bias ? bias[n] : 0.f;
#pragma unroll
            for (int r = 0; r < 4; ++r) {
                int m = m0 + wm + i * 16 + fq * 4 + r;
                float v = acc[i][j][r] + bv;
                if (res) v += res[(size_t)m * N + n];
                if (flags & 8) v *= 0.17677669529663687f;  // 1/sqrt(32)
                if (flags & 1) v = fmaxf(v, 0.f);
                if (flags & 4)
                    ((u16*)outp)[(((size_t)(m >> 9)) * 256 + n) * 512 + (m & 511)] = f2bf(v);
                else if (flags & 2)
                    ((u16*)outp)[(size_t)m * N + n] = f2bf(v);
                else
                    ((float*)outp)[(size_t)m * N + n] = v;
            }
        }
    }
}

// ---------------------------------------------------------------------------
// bf16 MFMA implicit-GEMM conv1d (stride 2, taps 15 padded to 16).
__global__ __launch_bounds__(256) void maeeg_convmm_kernel(
    const u16* __restrict__ Wp, const u16* __restrict__ inp,
    const float* __restrict__ cb, float* __restrict__ out,
    int K3, int len_in, int len_out)
{
    __shared__ u16 As[8192];
    __shared__ u16 Bs[8192];
    const int m0 = blockIdx.x * 128, t0 = blockIdx.y * 128, b = blockIdx.z;
    const int lip = len_in + 16;
    const u16* inb = inp + (size_t)b * (K3 >> 4) * lip;
    const int t = threadIdx.x, w = t >> 6, lane = t & 63;
    const int sr = lane & 7, sc = lane >> 3;
    const int fr = lane & 15, fq = lane >> 4;
    const int wm = (w >> 1) * 64, wn = (w & 1) * 64;

    f32x4 acc[4][4];
    const f32x4 zero = {0.f, 0.f, 0.f, 0.f};
#pragma unroll
    for (int i = 0; i < 4; ++i)
#pragma unroll
        for (int j = 0; j < 4; ++j) acc[i][j] = zero;

    for (int k0 = 0; k0 < K3; k0 += 64) {
#pragma unroll
        for (int j = 0; j < 4; ++j) {
            int row = w * 32 + j * 8 + sr;
            uint4 va = *(const uint4*)(Wp + (size_t)(m0 + row) * K3 + k0 + sc * 8);
            int k  = k0 + sc * 8;
            int ci = k >> 4, rr = k & 15;
            int tg = t0 + row;
            const u16* gp = inb + (size_t)ci * lip + 2 * tg + rr;
            uint4 vb;
            vb.x = *(const u32*)(gp);
            vb.y = *(const u32*)(gp + 2);
            vb.z = *(const u32*)(gp + 4);
            vb.w = *(const u32*)(gp + 6);
            int kb = (sc ^ (row & 7)) << 4;
            *(uint4*)((char*)As + row * 128 + kb) = va;
            *(uint4*)((char*)Bs + row * 128 + kb) = vb;
        }
        __syncthreads();
#pragma unroll
        for (int kc = 0; kc < 2; ++kc) {
            bf16x8 af[4], bfv[4];
#pragma unroll
            for (int i = 0; i < 4; ++i) {
                int am = wm + i * 16 + fr;
                int bn = wn + i * 16 + fr;
                int kb = kc * 64 + fq * 16;
                af[i]  = *(const bf16x8*)((const char*)As + am * 128 + (kb ^ ((am & 7) << 4)));
                bfv[i] = *(const bf16x8*)((const char*)Bs + bn * 128 + (kb ^ ((bn & 7) << 4)));
            }
#pragma unroll
            for (int i = 0; i < 4; ++i)
#pragma unroll
                for (int j = 0; j < 4; ++j)
                    acc[i][j] = __builtin_amdgcn_mfma_f32_16x16x32_bf16(
                        af[i], bfv[j], acc[i][j], 0, 0, 0);
        }
        __syncthreads();
    }
#pragma unroll
    for (int i = 0; i < 4; ++i) {
#pragma unroll
        for (int r = 0; r < 4; ++r) {
            int m = m0 + wm + i * 16 + fq * 4 + r;
            float bb = cb[m];
            float* op = out + ((size_t)b * 256 + m) * len_out + t0;
#pragma unroll
            for (int j = 0; j < 4; ++j)
                op[wn + j * 16 + fr] = acc[i][j][r] + bb;
        }
    }
}

// ---------------------------------------------------------------------------
// MFMA flash attention. Qb,Kb bf16 [B,512,256] (head cols h*32, Q pre-scaled);
// Vt bf16 [B,256,512]; out bf16 [B,512,256]. grid (4,8,32), 256 thr (4 waves).
__global__ __launch_bounds__(256) void maeeg_fattn_kernel(
    const u16* __restrict__ Qb, const u16* __restrict__ Kb,
    const u16* __restrict__ Vt, u16* __restrict__ att)
{
    __shared__ u16 Ks[64 * 32];      // [64 kk][32 d], 64B rows, chunk^=(kk&3)
    __shared__ u16 Vs[32 * 64];      // [32 d][64 kk], 128B rows, chunk^=(d&7)
    __shared__ u16 Ps[4][32 * 64];   // per-wave [32 q][64 kk], chunk^=(q&7)
    const int qt = blockIdx.x, h = blockIdx.y, b = blockIdx.z;
    const int t = threadIdx.x, w = t >> 6, lane = t & 63;
    const int fr = lane & 15, fq = lane >> 4;
    const u16* qbase = Qb + (size_t)b * 512 * 256 + h * 32;
    const u16* kbase = Kb + (size_t)b * 512 * 256 + h * 32;
    const u16* vbase = Vt + (size_t)b * 256 * 512 + (size_t)h * 32 * 512;

    bf16x8 qf[2];
#pragma unroll
    for (int mi = 0; mi < 2; ++mi)
        qf[mi] = *(const bf16x8*)(qbase +
                 (size_t)(qt * 128 + w * 32 + mi * 16 + fr) * 256 + fq * 8);

    f32x4 oacc[2][2];
    const f32x4 zero = {0.f, 0.f, 0.f, 0.f};
    oacc[0][0] = zero; oacc[0][1] = zero; oacc[1][0] = zero; oacc[1][1] = zero;
    float mrun[8], lrun[8];
#pragma unroll
    for (int i = 0; i < 8; ++i) { mrun[i] = -1e30f; lrun[i] = 0.f; }

    for (int kt = 0; kt < 512; kt += 64) {
        {   // stage K tile (4KB) + Vt tile (4KB), swizzled
            int row = t >> 2, c = t & 3;
            uint4 kv = *(const uint4*)(kbase + (size_t)(kt + row) * 256 + c * 8);
            *(uint4*)((char*)Ks + row * 64 + (((c ^ (row & 3)) << 4))) = kv;
            int d = t >> 3, c2 = t & 7;
            uint4 vv = *(const uint4*)(vbase + (size_t)d * 512 + kt + c2 * 8);
            *(uint4*)((char*)Vs + d * 128 + ((c2 ^ (d & 7)) << 4)) = vv;
        }
        __syncthreads();

        // ---- QK^T: S[32 q][64 kk] ----
        f32x4 sacc[2][4];
#pragma unroll
        for (int mi = 0; mi < 2; ++mi)
#pragma unroll
            for (int ni = 0; ni < 4; ++ni) sacc[mi][ni] = zero;
        bf16x8 kf[4];
#pragma unroll
        for (int ni = 0; ni < 4; ++ni) {
            int kk = ni * 16 + fr;
            kf[ni] = *(const bf16x8*)((const char*)Ks + kk * 64 +
                                      ((fq ^ (kk & 3)) << 4));
        }
#pragma unroll
        for (int mi = 0; mi < 2; ++mi)
#pragma unroll
            for (int ni = 0; ni < 4; ++ni)
                sacc[mi][ni] = __builtin_amdgcn_mfma_f32_16x16x32_bf16(
                    qf[mi], kf[ni], sacc[mi][ni], 0, 0, 0);

        // ---- online softmax (rows = fq*4+reg per 16-block) ----
#pragma unroll
        for (int mi = 0; mi < 2; ++mi) {
#pragma unroll
            for (int reg = 0; reg < 4; ++reg) {
                int idx = mi * 4 + reg;
                float rm = fmaxf(fmaxf(sacc[mi][0][reg], sacc[mi][1][reg]),
                                 fmaxf(sacc[mi][2][reg], sacc[mi][3][reg]));
                rm = fmaxf(rm, __shfl_xor(rm, 1));
                rm = fmaxf(rm, __shfl_xor(rm, 2));
                rm = fmaxf(rm, __shfl_xor(rm, 4));
                rm = fmaxf(rm, __shfl_xor(rm, 8));
                float mold = mrun[idx];
                float mnew = fmaxf(mold, rm);
                float c = __expf(mold - mnew);
                mrun[idx] = mnew;
                int q = mi * 16 + fq * 4 + reg;
                float psum = 0.f;
#pragma unroll
                for (int ni = 0; ni < 4; ++ni) {
                    float p = __expf(sacc[mi][ni][reg] - mnew);
                    psum += p;
                    int kk = ni * 16 + fr;
                    int boff = q * 128 + ((((kk >> 3) ^ (q & 7)) << 4) | ((kk & 7) << 1));
                    *(u16*)((char*)Ps[w] + boff) = f2bf(p);
                }
                lrun[idx] = lrun[idx] * c + psum;
                oacc[mi][0][reg] *= c;
                oacc[mi][1][reg] *= c;
            }
        }

        // ---- PV: O[32 q][32 d] += P @ V ----
        bf16x8 pf[2][2], vf[2][2];
#pragma unroll
        for (int mi = 0; mi < 2; ++mi)
#pragma unroll
            for (int kc = 0; kc < 2; ++kc) {
                int q = mi * 16 + fr;
                int ch = (kc * 4 + fq) ^ (q & 7);
                pf[mi][kc] = *(const bf16x8*)((const char*)Ps[w] + q * 128 + (ch << 4));
            }
#pragma unroll
        for (int nj = 0; nj < 2; ++nj)
#pragma unroll
            for (int kc = 0; kc < 2; ++kc) {
                int d = nj * 16 + fr;
                int ch = (kc * 4 + fq) ^ (d & 7);
                vf[nj][kc] = *(const bf16x8*)((const char*)Vs + d * 128 + (ch << 4));
            }
#pragma unroll
        for (int mi = 0; mi < 2; ++mi)
#pragma unroll
            for (int nj = 0; nj < 2; ++nj) {
                oacc[mi][nj] = __builtin_amdgcn_mfma_f32_16x16x32_bf16(
                    pf[mi][0], vf[nj][0], oacc[mi][nj], 0, 0, 0);
                oacc[mi][nj] = __builtin_amdgcn_mfma_f32_16x16x32_bf16(
                    pf[mi][1], vf[nj][1], oacc[mi][nj], 0, 0, 0);
            }
        __syncthreads();
    }

    // ---- epilogue: reduce l across 16-lane group, normalize, store ----
#pragma unroll
    for (int idx = 0; idx < 8; ++idx) {
        float l = lrun[idx];
        l += __shfl_xor(l, 1);
        l += __shfl_xor(l, 2);
        l += __shfl_xor(l, 4);
        l += __shfl_xor(l, 8);
        lrun[idx] = 1.f / l;
    }
    u16* ob = att + (size_t)b * 512 * 256 + h * 32;
#pragma unroll
    for (int mi = 0; mi < 2; ++mi)
#pragma unroll
        for (int reg = 0; reg < 4; ++reg) {
            int q = qt * 128 + w * 32 + mi * 16 + fq * 4 + reg;
            float inv = lrun[mi * 4 + reg];
#pragma unroll
            for (int nj = 0; nj < 2; ++nj)
                ob[(size_t)q * 256 + nj * 16 + fr] =
                    f2bf(oacc[mi][nj][reg] * inv);
        }
}

// ---------------------------------------------------------------------------
// weight prep: fp32 [O][CIN][15] -> bf16 [O][CIN*16] (tap 15 = 0)
__global__ void maeeg_prep_convw_kernel(const float* __restrict__ src,
                                        u16* __restrict__ dst, int n)
{
    int i = blockIdx.x * 256 + threadIdx.x;
    if (i >= n) return;
    int r = i & 15, base = i >> 4;
    dst[i] = (r < 15) ? f2bf(src[(size_t)base * 15 + r]) : (u16)0;
}

__global__ void maeeg_cast_kernel(const float* __restrict__ src,
                                  u16* __restrict__ dst, int n)
{
    int i = blockIdx.x * 256 + threadIdx.x;
    if (i < n) dst[i] = f2bf(src[i]);
}

// fp32 [rows][len] -> bf16 [rows][len+16], 7 leading zeros per row
__global__ void maeeg_cast_pad_kernel(const float* __restrict__ src,
                                      u16* __restrict__ dst, int len)
{
    int lip = len + 16;
    int p = blockIdx.x * 256 + threadIdx.x;
    int row = blockIdx.y;
    if (p >= lip) return;
    int q = p - 7;
    dst[(size_t)row * lip + p] =
        (q >= 0 && q < len) ? f2bf(src[(size_t)row * len + q]) : (u16)0;
}

// ---------------------------------------------------------------------------
// GroupNorm (2 ch/group) + exact GELU, in place; optional padded bf16 shadow.
__global__ __launch_bounds__(256) void maeeg_gn_gelu_kernel(
    float* __restrict__ h, const float* __restrict__ g,
    const float* __restrict__ bta, int len, u16* __restrict__ bfout, int lip)
{
    const int grp = blockIdx.x, b = blockIdx.y;
    float* p = h + ((size_t)b * 256 + grp * 2) * len;
    const int n = 2 * len;
    float s1 = 0.f, s2 = 0.f;
    for (int i = threadIdx.x; i < n; i += 256) {
        float v = p[i];
        s1 += v; s2 += v * v;
    }
    __shared__ float sc[4];
    float S1 = maeeg_block_sum(s1, sc);
    float S2 = maeeg_block_sum(s2, sc);
    float mu = S1 / (float)n;
    float var = fmaxf(S2 / (float)n - mu * mu, 0.f);
    float rs = rsqrtf(var + 1e-5f);
    float g0 = g[grp * 2], g1 = g[grp * 2 + 1];
    float b0 = bta[grp * 2], b1 = bta[grp * 2 + 1];
    u16* bp = bfout ? bfout + ((size_t)b * 256 + grp * 2) * lip : (u16*)0;
    for (int i = threadIdx.x; i < n; i += 256) {
        float v = (p[i] - mu) * rs;
        float y = (i < len) ? (v * g0 + b0) : (v * g1 + b1);
        float ge = 0.5f * y * (1.f + erff(y * 0.70710678118654752f));
        p[i] = ge;
        if (bp) bp[(i < len ? i : (i - len) + lip) + 7] = f2bf(ge);
    }
    if (bp && threadIdx.x < 32) {
        int ch = threadIdx.x >> 4, pp = threadIdx.x & 15;
        bp[(size_t)ch * lip + ((pp < 7) ? pp : (len + pp))] = 0;
    }
}

// ---------------------------------------------------------------------------
// transpose [B,256,512] -> [B,512,256], add sinusoidal pos enc; fp32 + bf16.
__global__ __launch_bounds__(256) void maeeg_transpose_pos_kernel(
    const float* __restrict__ in, float* __restrict__ out,
    u16* __restrict__ outb)
{
    __shared__ float tile[256][33];
    const int s0 = blockIdx.x * 32, b = blockIdx.y;
    for (int idx = threadIdx.x; idx < 256 * 32; idx += 256) {
        int e = idx >> 5, j = idx & 31;
        tile[e][j] = in[((size_t)b * 256 + e) * 512 + s0 + j];
    }
    __syncthreads();
    for (int idx = threadIdx.x; idx < 32 * 256; idx += 256) {
        int j = idx >> 8, e = idx & 255;
        float s = (float)(s0 + j);
        float ang = s / powf(10000.f, (float)e * (1.f / 256.f));
        float pe = (e & 1) ? cosf(ang) : sinf(ang);
        float v = tile[e][j] + pe;
        size_t o = ((size_t)b * 512 + s0 + j) * 256 + e;
        out[o] = v;
        outb[o] = f2bf(v);
    }
}

// ---------------------------------------------------------------------------
// LayerNorm over E=256 + bf16 shadow (one block per row)
__global__ __launch_bounds__(256) void maeeg_ln_kernel(
    const float* __restrict__ in, float* __restrict__ out,
    u16* __restrict__ bfout, const float* __restrict__ g,
    const float* __restrict__ b)
{
    const int m = blockIdx.x, t = threadIdx.x;
    float x = in[(size_t)m * 256 + t];
    __shared__ float sc[4];
    float mu = maeeg_block_sum(x, sc) * (1.f / 256.f);
    float d = x - mu;
    float var = maeeg_block_sum(d * d, sc) * (1.f / 256.f);
    float v = d * rsqrtf(var + 1e-5f) * g[t] + b[t];
    out[(size_t)m * 256 + t] = v;
    bfout[(size_t)m * 256 + t] = f2bf(v);
}

// ---------------------------------------------------------------------------
// classifier (fp32, Wc1 read once from HBM)
__global__ __launch_bounds__(256) void maeeg_cls1_kernel(
    const float* __restrict__ flat, const float* __restrict__ Wc1,
    float* __restrict__ part)
{
    const int ks = blockIdx.x, jt = blockIdx.y, t = threadIdx.x;
    const int jl = t & 63, bg = t >> 6;
    __shared__ float fsh[32][257];
    __shared__ float wsh[64][257];
    float acc[8];
#pragma unroll
    for (int i = 0; i < 8; ++i) acc[i] = 0.f;
    for (int kkc = 0; kkc < 8; ++kkc) {
        int kbase = ks * 2048 + kkc * 256;
        for (int idx = t; idx < 32 * 256; idx += 256) {
            int r = idx >> 8, c = idx & 255;
            fsh[r][c] = flat[(size_t)r * 131072 + kbase + c];
        }
        for (int idx = t; idx < 64 * 256; idx += 256) {
            int r = idx >> 8, c = idx & 255;
            wsh[r][c] = Wc1[(size_t)(jt * 64 + r) * 131072 + kbase + c];
        }
        __syncthreads();
        for (int i = 0; i < 256; ++i) {
            float wv = wsh[jl][i];
#pragma unroll
            for (int bb = 0; bb < 8; ++bb) acc[bb] += wv * fsh[bg * 8 + bb][i];
        }
        __syncthreads();
    }
#pragma unroll
    for (int bb = 0; bb < 8; ++bb)
        part[((size_t)ks * 32 + bg * 8 + bb) * 256 + jt * 64 + jl] = acc[bb];
}

__global__ void maeeg_cls2_kernel(const float* __restrict__ part,
                                  const float* __restrict__ bc1,
                                  float* __restrict__ hid)
{
    const int b = blockIdx.x, j = threadIdx.x;
    float s = bc1[j];
    for (int ks = 0; ks < 64; ++ks) s += part[((size_t)ks * 32 + b) * 256 + j];
    hid[b * 256 + j] = fmaxf(s, 0.f);
}

__global__ void maeeg_cls3_kernel(const float* __restrict__ hid,
                                  const float* __restrict__ Wc2,
                                  const float* __restrict__ bc2,
                                  float* __restrict__ out)
{
    const int b = blockIdx.x, t = threadIdx.x;
    float v = hid[b * 256 + t] * Wc2[t];
#pragma unroll
    for (int off = 32; off; off >>= 1) v += __shfl_down(v, off);
    __shared__ float r[4];
    if ((t & 63) == 0) r[t >> 6] = v;
    __syncthreads();
    if (t == 0) {
        float s = r[0] + r[1] + r[2] + r[3] + bc2[0];
        out[b] = 1.f / (1.f + expf(-s));
    }
}

// ===========================================================================
extern "C" void kernel_launch(void* const* d_in, const int* in_sizes, int n_in,
                              void* d_out, int out_size, void* d_ws, size_t ws_size,
                              hipStream_t stream)
{
    (void)in_sizes; (void)n_in; (void)out_size; (void)ws_size;
    const float* x        = (const float*)d_in[0];
    const float* conv0_w  = (const float*)d_in[1];
    const float* conv0_b  = (const float*)d_in[2];
    const float* conv12_w = (const float*)d_in[3];
    const float* conv12_b = (const float*)d_in[4];
    const float* gn_g     = (const float*)d_in[5];
    const float* gn_b     = (const float*)d_in[6];
    const float* Wq       = (const float*)d_in[7];
    const float* Wk       = (const float*)d_in[8];
    const float* Wv       = (const float*)d_in[9];
    const float* Wo       = (const float*)d_in[10];
    const float* ln1_g    = (const float*)d_in[11];
    const float* ln1_b    = (const float*)d_in[12];
    const float* Wf1      = (const float*)d_in[13];
    const float* bf1      = (const float*)d_in[14];
    const float* Wf2      = (const float*)d_in[15];
    const float* bf2      = (const float*)d_in[16];
    const float* ln2_g    = (const float*)d_in[17];
    const float* ln2_b    = (const float*)d_in[18];
    const float* Wc1      = (const float*)d_in[19];
    const float* bc1      = (const float*)d_in[20];
    const float* Wc2      = (const float*)d_in[21];
    const float* bc2      = (const float*)d_in[22];
    float* out = (float*)d_out;

    // ---- workspace layout (bytes, all 256-aligned) ----
    char* wsb = (char*)d_ws;
    u16* WB0   = (u16*)(wsb + 0);
    u16* WB12  = (u16*)(wsb + 524288);
    u16* WQb   = (u16*)(wsb + 4718592);
    u16* WKb   = (u16*)(wsb + 5242880);
    u16* WVb   = (u16*)(wsb + 5767168);
    u16* WOb   = (u16*)(wsb + 6291456);
    u16* WF1b  = (u16*)(wsb + 6815744);
    u16* WF2b  = (u16*)(wsb + 8912896);
    // R1 (17,039,360 B): XPAD -> GN1B -> D
    u16*   XPAD  = (u16*)(wsb + 11010048);
    u16*   GN1B  = (u16*)(wsb + 11010048);
    float* D     = (float*)(wsb + 11010048);
    // R2 (67,108,864 B)
    float* CONV0 = (float*)(wsb + 28049408);
    float* CONV1 = (float*)(wsb + 28049408);
    float* CONV2 = (float*)(wsb + 28049408 + 33554432);
    u16*   Qb2   = (u16*)(wsb + 28049408);              // 8,388,608
    u16*   Kb2   = (u16*)(wsb + 28049408 + 8388608);
    u16*   Vt2   = (u16*)(wsb + 28049408 + 16777216);
    u16*   ATTb  = (u16*)(wsb + 28049408 + 25165824);
    u16*   Db    = (u16*)(wsb + 28049408 + 33554432);
    u16*   F1b   = (u16*)(wsb + 28049408);              // 33,554,432
    // R3 (33,816,576 B): GN0B -> C + Cb
    u16*   GN0B  = (u16*)(wsb + 95158272);
    float* C     = (float*)(wsb + 95158272);
    u16*   Cb    = (u16*)(wsb + 95158272 + 16777216);
    // R4
    float* PART  = (float*)(wsb + 128974848);
    float* HID   = (float*)(wsb + 128974848 + 2097152);

    // ---- weight prep (bf16 shadows) ----
    maeeg_prep_convw_kernel<<<1024, 256, 0, stream>>>(conv0_w, WB0, 262144);
    maeeg_prep_convw_kernel<<<8192, 256, 0, stream>>>(conv12_w, WB12, 2097152);
    maeeg_cast_kernel<<<1024, 256, 0, stream>>>(Wq, WQb, 262144);
    maeeg_cast_kernel<<<1024, 256, 0, stream>>>(Wk, WKb, 262144);
    maeeg_cast_kernel<<<1024, 256, 0, stream>>>(Wv, WVb, 262144);
    maeeg_cast_kernel<<<1024, 256, 0, stream>>>(Wo, WOb, 262144);
    maeeg_cast_kernel<<<4096, 256, 0, stream>>>(Wf1, WF1b, 1048576);
    maeeg_cast_kernel<<<4096, 256, 0, stream>>>(Wf2, WF2b, 1048576);
    maeeg_cast_pad_kernel<<<dim3(17, 2048), 256, 0, stream>>>(x, XPAD, 4096);

    // ---- conv encoder ----
    maeeg_convmm_kernel<<<dim3(2, 16, 32), 256, 0, stream>>>(
        WB0, XPAD, conv0_b, CONV0, 1024, 4096, 2048);
    maeeg_gn_gelu_kernel<<<dim3(128, 32), 256, 0, stream>>>(
        CONV0, gn_g, gn_b, 2048, GN0B, 2064);
    maeeg_convmm_kernel<<<dim3(2, 8, 32), 256, 0, stream>>>(
        WB12, GN0B, conv12_b, CONV1, 4096, 2048, 1024);
    maeeg_gn_gelu_kernel<<<dim3(128, 32), 256, 0, stream>>>(
        CONV1, gn_g + 256, gn_b + 256, 1024, GN1B, 1040);
    maeeg_convmm_kernel<<<dim3(2, 4, 32), 256, 0, stream>>>(
        WB12 + 256 * 4096, GN1B, conv12_b + 256, CONV2, 4096, 1024, 512);
    maeeg_gn_gelu_kernel<<<dim3(128, 32), 256, 0, stream>>>(
        CONV2, gn_g + 512, gn_b + 512, 512, (u16*)0, 0);
    maeeg_transpose_pos_kernel<<<dim3(16, 32), 256, 0, stream>>>(CONV2, C, Cb);

    // ---- transformer encoder ----
    for (int l = 0; l < 4; ++l) {
        maeeg_mm_kernel<<<dim3(128, 2), 256, 0, stream>>>(
            Cb, WQb + l * 65536, (const float*)0, (const float*)0, Qb2, 256, 256, 10);
        maeeg_mm_kernel<<<dim3(128, 2), 256, 0, stream>>>(
            Cb, WKb + l * 65536, (const float*)0, (const float*)0, Kb2, 256, 256, 2);
        maeeg_mm_kernel<<<dim3(128, 2), 256, 0, stream>>>(
            Cb, WVb + l * 65536, (const float*)0, (const float*)0, Vt2, 256, 256, 4);
        maeeg_fattn_kernel<<<dim3(4, 8, 32), 256, 0, stream>>>(Qb2, Kb2, Vt2, ATTb);
        maeeg_mm_kernel<<<dim3(128, 2), 256, 0, stream>>>(
            ATTb, WOb + l * 65536, (const float*)0, C, D, 256, 256, 0);
        maeeg_ln_kernel<<<16384, 256, 0, stream>>>(
            D, D, Db, ln1_g + l * 256, ln1_b + l * 256);
        maeeg_mm_kernel<<<dim3(128, 8), 256, 0, stream>>>(
            Db, WF1b + l * 262144, bf1 + l * 1024, (const float*)0, F1b, 1024, 256, 3);
        maeeg_mm_kernel<<<dim3(128, 2), 256, 0, stream>>>(
            F1b, WF2b + l * 262144, bf2 + l * 256, D, C, 256, 1024, 0);
        maeeg_ln_kernel<<<16384, 256, 0, stream>>>(
            C, C, Cb, ln2_g + l * 256, ln2_b + l * 256);
    }

    // ---- classifier ----
    maeeg_cls1_kernel<<<dim3(64, 4), 256, 0, stream>>>(C, Wc1, PART);
    maeeg_cls2_kernel<<<32, 256, 0, stream>>>(PART, bc1, HID);
    maeeg_cls3_kernel<<<32, 256, 0, stream>>>(HID, Wc2, bc2, out);
}

// Round 4
// 1309.527 us; speedup vs baseline: 4.8960x; 1.1236x over previous
//
#include <hip/hip_runtime.h>
#include <math.h>

// ============================================================================
// MAEEG classification, round 4:
//   - cls1 rewritten as MFMA split-K GEMM with INLINE fp32->bf16 conversion of
//     Wc1 (single HBM pass over the 134MB weight, no separate cast kernel);
//     flat operand = Cb (bf16 shadow of final LN) which IS flat[32][131072].
//     grid (128 ks, 4 jt), 12KB LDS, 2 blocks/CU.
//   - QKV projections fused into ONE mm dispatch (N=768, packed weights);
//     epilogue routes seg0->Q(scaled), seg1->K, seg2->V-transposed.
//   - sinusoidal PE hoisted to a one-time [512][256] table.
//   - everything else as round 3 (MFMA convs, MFMA flash attention, fp32
//     master activation path with fused bf16 shadows).
// ============================================================================

typedef unsigned int   u32;
typedef unsigned short u16;
typedef __attribute__((ext_vector_type(4))) float f32x4;
typedef __attribute__((ext_vector_type(8))) short bf16x8;

__device__ __forceinline__ u16 f2bf(float v) {
    union { float f; u32 u; } x; x.f = v;
    u32 r = x.u + 0x7fffu + ((x.u >> 16) & 1u);  // RNE
    return (u16)(r >> 16);
}

// ---------------------------------------------------------------------------
__device__ __forceinline__ float maeeg_block_sum(float v, float* sc4) {
#pragma unroll
    for (int off = 32; off; off >>= 1) v += __shfl_down(v, off);
    int t = threadIdx.x;
    if ((t & 63) == 0) sc4[t >> 6] = v;
    __syncthreads();
    float r = sc4[0] + sc4[1] + sc4[2] + sc4[3];
    __syncthreads();
    return r;
}

// ---------------------------------------------------------------------------
// bf16 MFMA GEMM: out[m][n] = sum_k A[m][k]*B[n][k] (+bias[n]) (+res)
// flags: 1 relu | 2 bf16 out | 4 transposed bf16 out | 16 fused-QKV routing
__global__ __launch_bounds__(256) void maeeg_mm_kernel(
    const u16* __restrict__ Ag, const u16* __restrict__ Bg,
    const float* __restrict__ bias, const float* __restrict__ res,
    void* __restrict__ outp, int N, int K, int flags)
{
    __shared__ u16 As[8192];  // [128 rows][64 k] bf16, 128B/row, XOR-swizzled
    __shared__ u16 Bs[8192];
    const int m0 = blockIdx.x * 128, n0 = blockIdx.y * 128;
    const int t = threadIdx.x, w = t >> 6, lane = t & 63;
    const int sr = lane & 7, sc = lane >> 3;
    const int fr = lane & 15, fq = lane >> 4;
    const int wm = (w >> 1) * 64, wn = (w & 1) * 64;

    f32x4 acc[4][4];
    const f32x4 zero = {0.f, 0.f, 0.f, 0.f};
#pragma unroll
    for (int i = 0; i < 4; ++i)
#pragma unroll
        for (int j = 0; j < 4; ++j) acc[i][j] = zero;

    for (int k0 = 0; k0 < K; k0 += 64) {
#pragma unroll
        for (int j = 0; j < 4; ++j) {
            int row = w * 32 + j * 8 + sr;
            uint4 va = *(const uint4*)(Ag + (size_t)(m0 + row) * K + k0 + sc * 8);
            uint4 vb = *(const uint4*)(Bg + (size_t)(n0 + row) * K + k0 + sc * 8);
            int kb = (sc ^ (row & 7)) << 4;
            *(uint4*)((char*)As + row * 128 + kb) = va;
            *(uint4*)((char*)Bs + row * 128 + kb) = vb;
        }
        __syncthreads();
#pragma unroll
        for (int kc = 0; kc < 2; ++kc) {
            bf16x8 af[4], bfv[4];
#pragma unroll
            for (int i = 0; i < 4; ++i) {
                int am = wm + i * 16 + fr;
                int bn = wn + i * 16 + fr;
                int kb = kc * 64 + fq * 16;
                af[i]  = *(const bf16x8*)((const char*)As + am * 128 + (kb ^ ((am & 7) << 4)));
                bfv[i] = *(const bf16x8*)((const char*)Bs + bn * 128 + (kb ^ ((bn & 7) << 4)));
            }
#pragma unroll
            for (int i = 0; i < 4; ++i)
#pragma unroll
                for (int j = 0; j < 4; ++j)
                    acc[i][j] = __builtin_amdgcn_mfma_f32_16x16x32_bf16(
                        af[i], bfv[j], acc[i][j], 0, 0, 0);
        }
        __syncthreads();
    }
#pragma unroll
    for (int i = 0; i < 4; ++i) {
#pragma unroll
        for (int j = 0; j < 4; ++j) {
            int n = n0 + wn + j * 16 + fr;
            float bv = bias ? bias[n] : 0.f;
#pragma unroll
            for (int r = 0; r < 4; ++r) {
                int m = m0 + wm + i * 16 + fq * 4 + r;
                float v = acc[i][j][r] + bv;
                if (res) v += res[(size_t)m * N + n];
                if (flags & 1) v = fmaxf(v, 0.f);
                if (flags & 16) {
                    // fused QKV: seg0 -> Q (scaled), seg1 -> K, seg2 -> V^T
                    u16* o = (u16*)outp;
                    int seg = n >> 8, nn = n & 255;
                    if (seg == 0)
                        o[(size_t)m * 256 + nn] = f2bf(v * 0.17677669529663687f);
                    else if (seg == 1)
                        o[4194304 + (size_t)m * 256 + nn] = f2bf(v);
                    else
                        o[8388608 + (((size_t)(m >> 9)) * 256 + nn) * 512 + (m & 511)] = f2bf(v);
                } else if (flags & 4)
                    ((u16*)outp)[(((size_t)(m >> 9)) * 256 + n) * 512 + (m & 511)] = f2bf(v);
                else if (flags & 2)
                    ((u16*)outp)[(size_t)m * N + n] = f2bf(v);
                else
                    ((float*)outp)[(size_t)m * N + n] = v;
            }
        }
    }
}

// ---------------------------------------------------------------------------
// bf16 MFMA implicit-GEMM conv1d (stride 2, taps 15 padded to 16).
__global__ __launch_bounds__(256) void maeeg_convmm_kernel(
    const u16* __restrict__ Wp, const u16* __restrict__ inp,
    const float* __restrict__ cb, float* __restrict__ out,
    int K3, int len_in, int len_out)
{
    __shared__ u16 As[8192];
    __shared__ u16 Bs[8192];
    const int m0 = blockIdx.x * 128, t0 = blockIdx.y * 128, b = blockIdx.z;
    const int lip = len_in + 16;
    const u16* inb = inp + (size_t)b * (K3 >> 4) * lip;
    const int t = threadIdx.x, w = t >> 6, lane = t & 63;
    const int sr = lane & 7, sc = lane >> 3;
    const int fr = lane & 15, fq = lane >> 4;
    const int wm = (w >> 1) * 64, wn = (w & 1) * 64;

    f32x4 acc[4][4];
    const f32x4 zero = {0.f, 0.f, 0.f, 0.f};
#pragma unroll
    for (int i = 0; i < 4; ++i)
#pragma unroll
        for (int j = 0; j < 4; ++j) acc[i][j] = zero;

    for (int k0 = 0; k0 < K3; k0 += 64) {
#pragma unroll
        for (int j = 0; j < 4; ++j) {
            int row = w * 32 + j * 8 + sr;
            uint4 va = *(const uint4*)(Wp + (size_t)(m0 + row) * K3 + k0 + sc * 8);
            int k  = k0 + sc * 8;
            int ci = k >> 4, rr = k & 15;
            int tg = t0 + row;
            const u16* gp = inb + (size_t)ci * lip + 2 * tg + rr;
            uint4 vb;
            vb.x = *(const u32*)(gp);
            vb.y = *(const u32*)(gp + 2);
            vb.z = *(const u32*)(gp + 4);
            vb.w = *(const u32*)(gp + 6);
            int kb = (sc ^ (row & 7)) << 4;
            *(uint4*)((char*)As + row * 128 + kb) = va;
            *(uint4*)((char*)Bs + row * 128 + kb) = vb;
        }
        __syncthreads();
#pragma unroll
        for (int kc = 0; kc < 2; ++kc) {
            bf16x8 af[4], bfv[4];
#pragma unroll
            for (int i = 0; i < 4; ++i) {
                int am = wm + i * 16 + fr;
                int bn = wn + i * 16 + fr;
                int kb = kc * 64 + fq * 16;
                af[i]  = *(const bf16x8*)((const char*)As + am * 128 + (kb ^ ((am & 7) << 4)));
                bfv[i] = *(const bf16x8*)((const char*)Bs + bn * 128 + (kb ^ ((bn & 7) << 4)));
            }
#pragma unroll
            for (int i = 0; i < 4; ++i)
#pragma unroll
                for (int j = 0; j < 4; ++j)
                    acc[i][j] = __builtin_amdgcn_mfma_f32_16x16x32_bf16(
                        af[i], bfv[j], acc[i][j], 0, 0, 0);
        }
        __syncthreads();
    }
#pragma unroll
    for (int i = 0; i < 4; ++i) {
#pragma unroll
        for (int r = 0; r < 4; ++r) {
            int m = m0 + wm + i * 16 + fq * 4 + r;
            float bb = cb[m];
            float* op = out + ((size_t)b * 256 + m) * len_out + t0;
#pragma unroll
            for (int j = 0; j < 4; ++j)
                op[wn + j * 16 + fr] = acc[i][j][r] + bb;
        }
    }
}

// ---------------------------------------------------------------------------
// MFMA flash attention (unchanged from round 3).
__global__ __launch_bounds__(256) void maeeg_fattn_kernel(
    const u16* __restrict__ Qb, const u16* __restrict__ Kb,
    const u16* __restrict__ Vt, u16* __restrict__ att)
{
    __shared__ u16 Ks[64 * 32];
    __shared__ u16 Vs[32 * 64];
    __shared__ u16 Ps[4][32 * 64];
    const int qt = blockIdx.x, h = blockIdx.y, b = blockIdx.z;
    const int t = threadIdx.x, w = t >> 6, lane = t & 63;
    const int fr = lane & 15, fq = lane >> 4;
    const u16* qbase = Qb + (size_t)b * 512 * 256 + h * 32;
    const u16* kbase = Kb + (size_t)b * 512 * 256 + h * 32;
    const u16* vbase = Vt + (size_t)b * 256 * 512 + (size_t)h * 32 * 512;

    bf16x8 qf[2];
#pragma unroll
    for (int mi = 0; mi < 2; ++mi)
        qf[mi] = *(const bf16x8*)(qbase +
                 (size_t)(qt * 128 + w * 32 + mi * 16 + fr) * 256 + fq * 8);

    f32x4 oacc[2][2];
    const f32x4 zero = {0.f, 0.f, 0.f, 0.f};
    oacc[0][0] = zero; oacc[0][1] = zero; oacc[1][0] = zero; oacc[1][1] = zero;
    float mrun[8], lrun[8];
#pragma unroll
    for (int i = 0; i < 8; ++i) { mrun[i] = -1e30f; lrun[i] = 0.f; }

    for (int kt = 0; kt < 512; kt += 64) {
        {
            int row = t >> 2, c = t & 3;
            uint4 kv = *(const uint4*)(kbase + (size_t)(kt + row) * 256 + c * 8);
            *(uint4*)((char*)Ks + row * 64 + (((c ^ (row & 3)) << 4))) = kv;
            int d = t >> 3, c2 = t & 7;
            uint4 vv = *(const uint4*)(vbase + (size_t)d * 512 + kt + c2 * 8);
            *(uint4*)((char*)Vs + d * 128 + ((c2 ^ (d & 7)) << 4)) = vv;
        }
        __syncthreads();

        f32x4 sacc[2][4];
#pragma unroll
        for (int mi = 0; mi < 2; ++mi)
#pragma unroll
            for (int ni = 0; ni < 4; ++ni) sacc[mi][ni] = zero;
        bf16x8 kf[4];
#pragma unroll
        for (int ni = 0; ni < 4; ++ni) {
            int kk = ni * 16 + fr;
            kf[ni] = *(const bf16x8*)((const char*)Ks + kk * 64 +
                                      ((fq ^ (kk & 3)) << 4));
        }
#pragma unroll
        for (int mi = 0; mi < 2; ++mi)
#pragma unroll
            for (int ni = 0; ni < 4; ++ni)
                sacc[mi][ni] = __builtin_amdgcn_mfma_f32_16x16x32_bf16(
                    qf[mi], kf[ni], sacc[mi][ni], 0, 0, 0);

#pragma unroll
        for (int mi = 0; mi < 2; ++mi) {
#pragma unroll
            for (int reg = 0; reg < 4; ++reg) {
                int idx = mi * 4 + reg;
                float rm = fmaxf(fmaxf(sacc[mi][0][reg], sacc[mi][1][reg]),
                                 fmaxf(sacc[mi][2][reg], sacc[mi][3][reg]));
                rm = fmaxf(rm, __shfl_xor(rm, 1));
                rm = fmaxf(rm, __shfl_xor(rm, 2));
                rm = fmaxf(rm, __shfl_xor(rm, 4));
                rm = fmaxf(rm, __shfl_xor(rm, 8));
                float mold = mrun[idx];
                float mnew = fmaxf(mold, rm);
                float c = __expf(mold - mnew);
                mrun[idx] = mnew;
                int q = mi * 16 + fq * 4 + reg;
                float psum = 0.f;
#pragma unroll
                for (int ni = 0; ni < 4; ++ni) {
                    float p = __expf(sacc[mi][ni][reg] - mnew);
                    psum += p;
                    int kk = ni * 16 + fr;
                    int boff = q * 128 + ((((kk >> 3) ^ (q & 7)) << 4) | ((kk & 7) << 1));
                    *(u16*)((char*)Ps[w] + boff) = f2bf(p);
                }
                lrun[idx] = lrun[idx] * c + psum;
                oacc[mi][0][reg] *= c;
                oacc[mi][1][reg] *= c;
            }
        }

        bf16x8 pf[2][2], vf[2][2];
#pragma unroll
        for (int mi = 0; mi < 2; ++mi)
#pragma unroll
            for (int kc = 0; kc < 2; ++kc) {
                int q = mi * 16 + fr;
                int ch = (kc * 4 + fq) ^ (q & 7);
                pf[mi][kc] = *(const bf16x8*)((const char*)Ps[w] + q * 128 + (ch << 4));
            }
#pragma unroll
        for (int nj = 0; nj < 2; ++nj)
#pragma unroll
            for (int kc = 0; kc < 2; ++kc) {
                int d = nj * 16 + fr;
                int ch = (kc * 4 + fq) ^ (d & 7);
                vf[nj][kc] = *(const bf16x8*)((const char*)Vs + d * 128 + (ch << 4));
            }
#pragma unroll
        for (int mi = 0; mi < 2; ++mi)
#pragma unroll
            for (int nj = 0; nj < 2; ++nj) {
                oacc[mi][nj] = __builtin_amdgcn_mfma_f32_16x16x32_bf16(
                    pf[mi][0], vf[nj][0], oacc[mi][nj], 0, 0, 0);
                oacc[mi][nj] = __builtin_amdgcn_mfma_f32_16x16x32_bf16(
                    pf[mi][1], vf[nj][1], oacc[mi][nj], 0, 0, 0);
            }
        __syncthreads();
    }

#pragma unroll
    for (int idx = 0; idx < 8; ++idx) {
        float l = lrun[idx];
        l += __shfl_xor(l, 1);
        l += __shfl_xor(l, 2);
        l += __shfl_xor(l, 4);
        l += __shfl_xor(l, 8);
        lrun[idx] = 1.f / l;
    }
    u16* ob = att + (size_t)b * 512 * 256 + h * 32;
#pragma unroll
    for (int mi = 0; mi < 2; ++mi)
#pragma unroll
        for (int reg = 0; reg < 4; ++reg) {
            int q = qt * 128 + w * 32 + mi * 16 + fq * 4 + reg;
            float inv = lrun[mi * 4 + reg];
#pragma unroll
            for (int nj = 0; nj < 2; ++nj)
                ob[(size_t)q * 256 + nj * 16 + fr] =
                    f2bf(oacc[mi][nj][reg] * inv);
        }
}

// ---------------------------------------------------------------------------
__global__ void maeeg_prep_convw_kernel(const float* __restrict__ src,
                                        u16* __restrict__ dst, int n)
{
    int i = blockIdx.x * 256 + threadIdx.x;
    if (i >= n) return;
    int r = i & 15, base = i >> 4;
    dst[i] = (r < 15) ? f2bf(src[(size_t)base * 15 + r]) : (u16)0;
}

__global__ void maeeg_cast_kernel(const float* __restrict__ src,
                                  u16* __restrict__ dst, int n)
{
    int i = blockIdx.x * 256 + threadIdx.x;
    if (i < n) dst[i] = f2bf(src[i]);
}

// pack Wq/Wk/Wv [L][65536] into WQKV [L][3][65536] at segment seg
__global__ void maeeg_cast_qkv_kernel(const float* __restrict__ src,
                                      u16* __restrict__ dst, int seg)
{
    int i = blockIdx.x * 256 + threadIdx.x;  // 0..262143
    int l = i >> 16, r = i & 65535;
    dst[(size_t)l * 196608 + seg * 65536 + r] = f2bf(src[i]);
}

__global__ void maeeg_cast_pad_kernel(const float* __restrict__ src,
                                      u16* __restrict__ dst, int len)
{
    int lip = len + 16;
    int p = blockIdx.x * 256 + threadIdx.x;
    int row = blockIdx.y;
    if (p >= lip) return;
    int q = p - 7;
    dst[(size_t)row * lip + p] =
        (q >= 0 && q < len) ? f2bf(src[(size_t)row * len + q]) : (u16)0;
}

// sinusoidal PE table [512][256]
__global__ void maeeg_pe_kernel(float* __restrict__ pet)
{
    int s = blockIdx.x, e = threadIdx.x;
    float ang = (float)s / powf(10000.f, (float)e * (1.f / 256.f));
    pet[s * 256 + e] = (e & 1) ? cosf(ang) : sinf(ang);
}

// ---------------------------------------------------------------------------
__global__ __launch_bounds__(256) void maeeg_gn_gelu_kernel(
    float* __restrict__ h, const float* __restrict__ g,
    const float* __restrict__ bta, int len, u16* __restrict__ bfout, int lip)
{
    const int grp = blockIdx.x, b = blockIdx.y;
    float* p = h + ((size_t)b * 256 + grp * 2) * len;
    const int n = 2 * len;
    float s1 = 0.f, s2 = 0.f;
    for (int i = threadIdx.x; i < n; i += 256) {
        float v = p[i];
        s1 += v; s2 += v * v;
    }
    __shared__ float sc[4];
    float S1 = maeeg_block_sum(s1, sc);
    float S2 = maeeg_block_sum(s2, sc);
    float mu = S1 / (float)n;
    float var = fmaxf(S2 / (float)n - mu * mu, 0.f);
    float rs = rsqrtf(var + 1e-5f);
    float g0 = g[grp * 2], g1 = g[grp * 2 + 1];
    float b0 = bta[grp * 2], b1 = bta[grp * 2 + 1];
    u16* bp = bfout ? bfout + ((size_t)b * 256 + grp * 2) * lip : (u16*)0;
    for (int i = threadIdx.x; i < n; i += 256) {
        float v = (p[i] - mu) * rs;
        float y = (i < len) ? (v * g0 + b0) : (v * g1 + b1);
        float ge = 0.5f * y * (1.f + erff(y * 0.70710678118654752f));
        p[i] = ge;
        if (bp) bp[(i < len ? i : (i - len) + lip) + 7] = f2bf(ge);
    }
    if (bp && threadIdx.x < 32) {
        int ch = threadIdx.x >> 4, pp = threadIdx.x & 15;
        bp[(size_t)ch * lip + ((pp < 7) ? pp : (len + pp))] = 0;
    }
}

// ---------------------------------------------------------------------------
// transpose [B,256,512] -> [B,512,256], add PE from table; fp32 + bf16.
__global__ __launch_bounds__(256) void maeeg_transpose_pos_kernel(
    const float* __restrict__ in, const float* __restrict__ pet,
    float* __restrict__ out, u16* __restrict__ outb)
{
    __shared__ float tile[256][33];
    const int s0 = blockIdx.x * 32, b = blockIdx.y;
    for (int idx = threadIdx.x; idx < 256 * 32; idx += 256) {
        int e = idx >> 5, j = idx & 31;
        tile[e][j] = in[((size_t)b * 256 + e) * 512 + s0 + j];
    }
    __syncthreads();
    for (int idx = threadIdx.x; idx < 32 * 256; idx += 256) {
        int j = idx >> 8, e = idx & 255;
        float v = tile[e][j] + pet[(s0 + j) * 256 + e];
        size_t o = ((size_t)b * 512 + s0 + j) * 256 + e;
        out[o] = v;
        outb[o] = f2bf(v);
    }
}

// ---------------------------------------------------------------------------
__global__ __launch_bounds__(256) void maeeg_ln_kernel(
    const float* __restrict__ in, float* __restrict__ out,
    u16* __restrict__ bfout, const float* __restrict__ g,
    const float* __restrict__ b)
{
    const int m = blockIdx.x, t = threadIdx.x;
    float x = in[(size_t)m * 256 + t];
    __shared__ float sc[4];
    float mu = maeeg_block_sum(x, sc) * (1.f / 256.f);
    float d = x - mu;
    float var = maeeg_block_sum(d * d, sc) * (1.f / 256.f);
    float v = d * rsqrtf(var + 1e-5f) * g[t] + b[t];
    out[(size_t)m * 256 + t] = v;
    bfout[(size_t)m * 256 + t] = f2bf(v);
}

// ---------------------------------------------------------------------------
// classifier stage 1: MFMA split-K. flatb bf16 [32][131072] (= Cb), Wc1 fp32
// converted inline to bf16. part[ks][32][256]. grid (128 ks, 4 jt), 256 thr.
__global__ __launch_bounds__(256) void maeeg_cls1_kernel(
    const u16* __restrict__ flatb, const float* __restrict__ Wc1,
    float* __restrict__ part)
{
    __shared__ u16 As[32 * 64];   // [32 m][64 k], 128B rows, swizzled
    __shared__ u16 Bs[64 * 64];   // [64 j][64 k]
    const int ks = blockIdx.x, jt = blockIdx.y;
    const int t = threadIdx.x, w = t >> 6, lane = t & 63;
    const int fr = lane & 15, fq = lane >> 4;
    const int kbase0 = ks * 1024;
    const int arow = t >> 3, ac = t & 7;   // A stage map
    const int brow = t >> 2, bq = t & 3;   // B stage map

    f32x4 acc[2];
    const f32x4 zero = {0.f, 0.f, 0.f, 0.f};
    acc[0] = zero; acc[1] = zero;

    for (int step = 0; step < 16; ++step) {
        int kk = kbase0 + step * 64;
        // A: 32 x 64 bf16 (flat)
        uint4 va = *(const uint4*)(flatb + (size_t)arow * 131072 + kk + ac * 8);
        *(uint4*)((char*)As + arow * 128 + ((ac ^ (arow & 7)) << 4)) = va;
        // B: 64 x 64, fp32 -> bf16 inline (each thread converts 16 floats)
        const float* wp = Wc1 + (size_t)(jt * 64 + brow) * 131072 + kk + bq * 16;
        float4 f0 = ((const float4*)wp)[0];
        float4 f1 = ((const float4*)wp)[1];
        float4 f2 = ((const float4*)wp)[2];
        float4 f3 = ((const float4*)wp)[3];
        uint4 p0, p1;
        p0.x = (u32)f2bf(f0.x) | ((u32)f2bf(f0.y) << 16);
        p0.y = (u32)f2bf(f0.z) | ((u32)f2bf(f0.w) << 16);
        p0.z = (u32)f2bf(f1.x) | ((u32)f2bf(f1.y) << 16);
        p0.w = (u32)f2bf(f1.z) | ((u32)f2bf(f1.w) << 16);
        p1.x = (u32)f2bf(f2.x) | ((u32)f2bf(f2.y) << 16);
        p1.y = (u32)f2bf(f2.z) | ((u32)f2bf(f2.w) << 16);
        p1.z = (u32)f2bf(f3.x) | ((u32)f2bf(f3.y) << 16);
        p1.w = (u32)f2bf(f3.z) | ((u32)f2bf(f3.w) << 16);
        int c0 = bq * 2, c1 = bq * 2 + 1;
        *(uint4*)((char*)Bs + brow * 128 + ((c0 ^ (brow & 7)) << 4)) = p0;
        *(uint4*)((char*)Bs + brow * 128 + ((c1 ^ (brow & 7)) << 4)) = p1;
        __syncthreads();
#pragma unroll
        for (int kc = 0; kc < 2; ++kc) {
            int kbyte = kc * 64 + fq * 16;
            int bn = w * 16 + fr;
            bf16x8 bfv = *(const bf16x8*)((const char*)Bs + bn * 128 +
                                          (kbyte ^ ((bn & 7) << 4)));
#pragma unroll
            for (int mi = 0; mi < 2; ++mi) {
                int am = mi * 16 + fr;
                bf16x8 af = *(const bf16x8*)((const char*)As + am * 128 +
                                             (kbyte ^ ((am & 7) << 4)));
                acc[mi] = __builtin_amdgcn_mfma_f32_16x16x32_bf16(
                    af, bfv, acc[mi], 0, 0, 0);
            }
        }
        __syncthreads();
    }
#pragma unroll
    for (int mi = 0; mi < 2; ++mi)
#pragma unroll
        for (int r = 0; r < 4; ++r) {
            int m = mi * 16 + fq * 4 + r;
            int j = jt * 64 + w * 16 + fr;
            part[((size_t)ks * 32 + m) * 256 + j] = acc[mi][r];
        }
}

__global__ void maeeg_cls2_kernel(const float* __restrict__ part,
                                  const float* __restrict__ bc1,
                                  float* __restrict__ hid)
{
    const int b = blockIdx.x, j = threadIdx.x;
    float s = bc1[j];
    for (int ks = 0; ks < 128; ++ks) s += part[((size_t)ks * 32 + b) * 256 + j];
    hid[b * 256 + j] = fmaxf(s, 0.f);
}

__global__ void maeeg_cls3_kernel(const float* __restrict__ hid,
                                  const float* __restrict__ Wc2,
                                  const float* __restrict__ bc2,
                                  float* __restrict__ out)
{
    const int b = blockIdx.x, t = threadIdx.x;
    float v = hid[b * 256 + t] * Wc2[t];
#pragma unroll
    for (int off = 32; off; off >>= 1) v += __shfl_down(v, off);
    __shared__ float r[4];
    if ((t & 63) == 0) r[t >> 6] = v;
    __syncthreads();
    if (t == 0) {
        float s = r[0] + r[1] + r[2] + r[3] + bc2[0];
        out[b] = 1.f / (1.f + expf(-s));
    }
}

// ===========================================================================
extern "C" void kernel_launch(void* const* d_in, const int* in_sizes, int n_in,
                              void* d_out, int out_size, void* d_ws, size_t ws_size,
                              hipStream_t stream)
{
    (void)in_sizes; (void)n_in; (void)out_size; (void)ws_size;
    const float* x        = (const float*)d_in[0];
    const float* conv0_w  = (const float*)d_in[1];
    const float* conv0_b  = (const float*)d_in[2];
    const float* conv12_w = (const float*)d_in[3];
    const float* conv12_b = (const float*)d_in[4];
    const float* gn_g     = (const float*)d_in[5];
    const float* gn_b     = (const float*)d_in[6];
    const float* Wq       = (const float*)d_in[7];
    const float* Wk       = (const float*)d_in[8];
    const float* Wv       = (const float*)d_in[9];
    const float* Wo       = (const float*)d_in[10];
    const float* ln1_g    = (const float*)d_in[11];
    const float* ln1_b    = (const float*)d_in[12];
    const float* Wf1      = (const float*)d_in[13];
    const float* bf1      = (const float*)d_in[14];
    const float* Wf2      = (const float*)d_in[15];
    const float* bf2      = (const float*)d_in[16];
    const float* ln2_g    = (const float*)d_in[17];
    const float* ln2_b    = (const float*)d_in[18];
    const float* Wc1      = (const float*)d_in[19];
    const float* bc1      = (const float*)d_in[20];
    const float* Wc2      = (const float*)d_in[21];
    const float* bc2      = (const float*)d_in[22];
    float* out = (float*)d_out;

    // ---- workspace layout (bytes) ----
    char* wsb = (char*)d_ws;
    u16* WB0   = (u16*)(wsb + 0);          //   524,288
    u16* WB12  = (u16*)(wsb + 524288);     // 4,194,304
    u16* WQKVb = (u16*)(wsb + 4718592);    // 1,572,864 [L][3][256][256]
    u16* WOb   = (u16*)(wsb + 6291456);    //   524,288
    u16* WF1b  = (u16*)(wsb + 6815744);    // 2,097,152
    u16* WF2b  = (u16*)(wsb + 8912896);    // 2,097,152 -> 11,010,048
    // R1: XPAD -> GN1B -> D
    u16*   XPAD  = (u16*)(wsb + 11010048);
    u16*   GN1B  = (u16*)(wsb + 11010048);
    float* D     = (float*)(wsb + 11010048);
    // R2 (67,108,864): CONV0 -> CONV1/CONV2 -> QKV/ATT/Db -> F1b
    float* CONV0 = (float*)(wsb + 28049408);
    float* CONV1 = (float*)(wsb + 28049408);
    float* CONV2 = (float*)(wsb + 28049408 + 33554432);
    u16*   Qb2   = (u16*)(wsb + 28049408);              // +0 (QKV packed base)
    u16*   ATTb  = (u16*)(wsb + 28049408 + 25165824);
    u16*   Db    = (u16*)(wsb + 28049408 + 33554432);
    u16*   F1b   = (u16*)(wsb + 28049408);
    // R3: GN0B -> C + Cb
    u16*   GN0B  = (u16*)(wsb + 95158272);
    float* C     = (float*)(wsb + 95158272);
    u16*   Cb    = (u16*)(wsb + 95158272 + 16777216);   // == flat bf16
    // R4
    float* PART  = (float*)(wsb + 128974848);           // 4,194,304
    float* HID   = (float*)(wsb + 133169152);           //    32,768
    float* PET   = (float*)(wsb + 133201920);           //   524,288

    // ---- weight prep ----
    maeeg_prep_convw_kernel<<<1024, 256, 0, stream>>>(conv0_w, WB0, 262144);
    maeeg_prep_convw_kernel<<<8192, 256, 0, stream>>>(conv12_w, WB12, 2097152);
    maeeg_cast_qkv_kernel<<<1024, 256, 0, stream>>>(Wq, WQKVb, 0);
    maeeg_cast_qkv_kernel<<<1024, 256, 0, stream>>>(Wk, WQKVb, 1);
    maeeg_cast_qkv_kernel<<<1024, 256, 0, stream>>>(Wv, WQKVb, 2);
    maeeg_cast_kernel<<<1024, 256, 0, stream>>>(Wo, WOb, 262144);
    maeeg_cast_kernel<<<4096, 256, 0, stream>>>(Wf1, WF1b, 1048576);
    maeeg_cast_kernel<<<4096, 256, 0, stream>>>(Wf2, WF2b, 1048576);
    maeeg_cast_pad_kernel<<<dim3(17, 2048), 256, 0, stream>>>(x, XPAD, 4096);
    maeeg_pe_kernel<<<512, 256, 0, stream>>>(PET);

    // ---- conv encoder ----
    maeeg_convmm_kernel<<<dim3(2, 16, 32), 256, 0, stream>>>(
        WB0, XPAD, conv0_b, CONV0, 1024, 4096, 2048);
    maeeg_gn_gelu_kernel<<<dim3(128, 32), 256, 0, stream>>>(
        CONV0, gn_g, gn_b, 2048, GN0B, 2064);
    maeeg_convmm_kernel<<<dim3(2, 8, 32), 256, 0, stream>>>(
        WB12, GN0B, conv12_b, CONV1, 4096, 2048, 1024);
    maeeg_gn_gelu_kernel<<<dim3(128, 32), 256, 0, stream>>>(
        CONV1, gn_g + 256, gn_b + 256, 1024, GN1B, 1040);
    maeeg_convmm_kernel<<<dim3(2, 4, 32), 256, 0, stream>>>(
        WB12 + 256 * 4096, GN1B, conv12_b + 256, CONV2, 4096, 1024, 512);
    maeeg_gn_gelu_kernel<<<dim3(128, 32), 256, 0, stream>>>(
        CONV2, gn_g + 512, gn_b + 512, 512, (u16*)0, 0);
    maeeg_transpose_pos_kernel<<<dim3(16, 32), 256, 0, stream>>>(CONV2, PET, C, Cb);

    // ---- transformer encoder ----
    for (int l = 0; l < 4; ++l) {
        maeeg_mm_kernel<<<dim3(128, 6), 256, 0, stream>>>(
            Cb, WQKVb + l * 196608, (const float*)0, (const float*)0,
            Qb2, 256, 256, 16);
        maeeg_fattn_kernel<<<dim3(4, 8, 32), 256, 0, stream>>>(
            Qb2, Qb2 + 4194304, Qb2 + 8388608, ATTb);
        maeeg_mm_kernel<<<dim3(128, 2), 256, 0, stream>>>(
            ATTb, WOb + l * 65536, (const float*)0, C, D, 256, 256, 0);
        maeeg_ln_kernel<<<16384, 256, 0, stream>>>(
            D, D, Db, ln1_g + l * 256, ln1_b + l * 256);
        maeeg_mm_kernel<<<dim3(128, 8), 256, 0, stream>>>(
            Db, WF1b + l * 262144, bf1 + l * 1024, (const float*)0, F1b, 1024, 256, 3);
        maeeg_mm_kernel<<<dim3(128, 2), 256, 0, stream>>>(
            F1b, WF2b + l * 262144, bf2 + l * 256, D, C, 256, 1024, 0);
        maeeg_ln_kernel<<<16384, 256, 0, stream>>>(
            C, C, Cb, ln2_g + l * 256, ln2_b + l * 256);
    }

    // ---- classifier ----
    maeeg_cls1_kernel<<<dim3(128, 4), 256, 0, stream>>>(Cb, Wc1, PART);
    maeeg_cls2_kernel<<<32, 256, 0, stream>>>(PART, bc1, HID);
    maeeg_cls3_kernel<<<32, 256, 0, stream>>>(HID, Wc2, bc2, out);
}

// Round 5
// 1305.765 us; speedup vs baseline: 4.9101x; 1.0029x over previous
//
#include <hip/hip_runtime.h>
#include <math.h>

// ============================================================================
// MAEEG classification, round 4:
//   - cls1 rewritten as MFMA split-K GEMM with INLINE fp32->bf16 conversion of
//     Wc1 (single HBM pass over the 134MB weight, no separate cast kernel);
//     flat operand = Cb (bf16 shadow of final LN) which IS flat[32][131072].
//     grid (128 ks, 4 jt), 12KB LDS, 2 blocks/CU.
//   - QKV projections fused into ONE mm dispatch (N=768, packed weights);
//     epilogue routes seg0->Q(scaled), seg1->K, seg2->V-transposed.
//   - sinusoidal PE hoisted to a one-time [512][256] table.
//   - everything else as round 3 (MFMA convs, MFMA flash attention, fp32
//     master activation path with fused bf16 shadows).
// ============================================================================

typedef unsigned int   u32;
typedef unsigned short u16;
typedef __attribute__((ext_vector_type(4))) float f32x4;
typedef __attribute__((ext_vector_type(8))) short bf16x8;

__device__ __forceinline__ u16 f2bf(float v) {
    union { float f; u32 u; } x; x.f = v;
    u32 r = x.u + 0x7fffu + ((x.u >> 16) & 1u);  // RNE
    return (u16)(r >> 16);
}

// ---------------------------------------------------------------------------
__device__ __forceinline__ float maeeg_block_sum(float v, float* sc4) {
#pragma unroll
    for (int off = 32; off; off >>= 1) v += __shfl_down(v, off);
    int t = threadIdx.x;
    if ((t & 63) == 0) sc4[t >> 6] = v;
    __syncthreads();
    float r = sc4[0] + sc4[1] + sc4[2] + sc4[3];
    __syncthreads();
    return r;
}

// ---------------------------------------------------------------------------
// bf16 MFMA GEMM: out[m][n] = sum_k A[m][k]*B[n][k] (+bias[n]) (+res)
// flags: 1 relu | 2 bf16 out | 4 transposed bf16 out | 16 fused-QKV routing
__global__ __launch_bounds__(256) void maeeg_mm_kernel(
    const u16* __restrict__ Ag, const u16* __restrict__ Bg,
    const float* __restrict__ bias, const float* __restrict__ res,
    void* __restrict__ outp, int N, int K, int flags)
{
    __shared__ u16 As[8192];  // [128 rows][64 k] bf16, 128B/row, XOR-swizzled
    __shared__ u16 Bs[8192];
    const int m0 = blockIdx.x * 128, n0 = blockIdx.y * 128;
    const int t = threadIdx.x, w = t >> 6, lane = t & 63;
    const int sr = lane & 7, sc = lane >> 3;
    const int fr = lane & 15, fq = lane >> 4;
    const int wm = (w >> 1) * 64, wn = (w & 1) * 64;

    f32x4 acc[4][4];
    const f32x4 zero = {0.f, 0.f, 0.f, 0.f};
#pragma unroll
    for (int i = 0; i < 4; ++i)
#pragma unroll
        for (int j = 0; j < 4; ++j) acc[i][j] = zero;

    for (int k0 = 0; k0 < K; k0 += 64) {
#pragma unroll
        for (int j = 0; j < 4; ++j) {
            int row = w * 32 + j * 8 + sr;
            uint4 va = *(const uint4*)(Ag + (size_t)(m0 + row) * K + k0 + sc * 8);
            uint4 vb = *(const uint4*)(Bg + (size_t)(n0 + row) * K + k0 + sc * 8);
            int kb = (sc ^ (row & 7)) << 4;
            *(uint4*)((char*)As + row * 128 + kb) = va;
            *(uint4*)((char*)Bs + row * 128 + kb) = vb;
        }
        __syncthreads();
#pragma unroll
        for (int kc = 0; kc < 2; ++kc) {
            bf16x8 af[4], bfv[4];
#pragma unroll
            for (int i = 0; i < 4; ++i) {
                int am = wm + i * 16 + fr;
                int bn = wn + i * 16 + fr;
                int kb = kc * 64 + fq * 16;
                af[i]  = *(const bf16x8*)((const char*)As + am * 128 + (kb ^ ((am & 7) << 4)));
                bfv[i] = *(const bf16x8*)((const char*)Bs + bn * 128 + (kb ^ ((bn & 7) << 4)));
            }
#pragma unroll
            for (int i = 0; i < 4; ++i)
#pragma unroll
                for (int j = 0; j < 4; ++j)
                    acc[i][j] = __builtin_amdgcn_mfma_f32_16x16x32_bf16(
                        af[i], bfv[j], acc[i][j], 0, 0, 0);
        }
        __syncthreads();
    }
#pragma unroll
    for (int i = 0; i < 4; ++i) {
#pragma unroll
        for (int j = 0; j < 4; ++j) {
            int n = n0 + wn + j * 16 + fr;
            float bv = bias ? bias[n] : 0.f;
#pragma unroll
            for (int r = 0; r < 4; ++r) {
                int m = m0 + wm + i * 16 + fq * 4 + r;
                float v = acc[i][j][r] + bv;
                if (res) v += res[(size_t)m * N + n];
                if (flags & 1) v = fmaxf(v, 0.f);
                if (flags & 16) {
                    // fused QKV: seg0 -> Q (scaled), seg1 -> K, seg2 -> V^T
                    u16* o = (u16*)outp;
                    int seg = n >> 8, nn = n & 255;
                    if (seg == 0)
                        o[(size_t)m * 256 + nn] = f2bf(v * 0.17677669529663687f);
                    else if (seg == 1)
                        o[4194304 + (size_t)m * 256 + nn] = f2bf(v);
                    else
                        o[8388608 + (((size_t)(m >> 9)) * 256 + nn) * 512 + (m & 511)] = f2bf(v);
                } else if (flags & 4)
                    ((u16*)outp)[(((size_t)(m >> 9)) * 256 + n) * 512 + (m & 511)] = f2bf(v);
                else if (flags & 2)
                    ((u16*)outp)[(size_t)m * N + n] = f2bf(v);
                else
                    ((float*)outp)[(size_t)m * N + n] = v;
            }
        }
    }
}

// ---------------------------------------------------------------------------
// bf16 MFMA implicit-GEMM conv1d (stride 2, taps 15 padded to 16).
__global__ __launch_bounds__(256) void maeeg_convmm_kernel(
    const u16* __restrict__ Wp, const u16* __restrict__ inp,
    const float* __restrict__ cb, float* __restrict__ out,
    int K3, int len_in, int len_out)
{
    __shared__ u16 As[8192];
    __shared__ u16 Bs[8192];
    const int m0 = blockIdx.x * 128, t0 = blockIdx.y * 128, b = blockIdx.z;
    const int lip = len_in + 16;
    const u16* inb = inp + (size_t)b * (K3 >> 4) * lip;
    const int t = threadIdx.x, w = t >> 6, lane = t & 63;
    const int sr = lane & 7, sc = lane >> 3;
    const int fr = lane & 15, fq = lane >> 4;
    const int wm = (w >> 1) * 64, wn = (w & 1) * 64;

    f32x4 acc[4][4];
    const f32x4 zero = {0.f, 0.f, 0.f, 0.f};
#pragma unroll
    for (int i = 0; i < 4; ++i)
#pragma unroll
        for (int j = 0; j < 4; ++j) acc[i][j] = zero;

    for (int k0 = 0; k0 < K3; k0 += 64) {
#pragma unroll
        for (int j = 0; j < 4; ++j) {
            int row = w * 32 + j * 8 + sr;
            uint4 va = *(const uint4*)(Wp + (size_t)(m0 + row) * K3 + k0 + sc * 8);
            int k  = k0 + sc * 8;
            int ci = k >> 4, rr = k & 15;
            int tg = t0 + row;
            const u16* gp = inb + (size_t)ci * lip + 2 * tg + rr;
            uint4 vb;
            vb.x = *(const u32*)(gp);
            vb.y = *(const u32*)(gp + 2);
            vb.z = *(const u32*)(gp + 4);
            vb.w = *(const u32*)(gp + 6);
            int kb = (sc ^ (row & 7)) << 4;
            *(uint4*)((char*)As + row * 128 + kb) = va;
            *(uint4*)((char*)Bs + row * 128 + kb) = vb;
        }
        __syncthreads();
#pragma unroll
        for (int kc = 0; kc < 2; ++kc) {
            bf16x8 af[4], bfv[4];
#pragma unroll
            for (int i = 0; i < 4; ++i) {
                int am = wm + i * 16 + fr;
                int bn = wn + i * 16 + fr;
                int kb = kc * 64 + fq * 16;
                af[i]  = *(const bf16x8*)((const char*)As + am * 128 + (kb ^ ((am & 7) << 4)));
                bfv[i] = *(const bf16x8*)((const char*)Bs + bn * 128 + (kb ^ ((bn & 7) << 4)));
            }
#pragma unroll
            for (int i = 0; i < 4; ++i)
#pragma unroll
                for (int j = 0; j < 4; ++j)
                    acc[i][j] = __builtin_amdgcn_mfma_f32_16x16x32_bf16(
                        af[i], bfv[j], acc[i][j], 0, 0, 0);
        }
        __syncthreads();
    }
#pragma unroll
    for (int i = 0; i < 4; ++i) {
#pragma unroll
        for (int r = 0; r < 4; ++r) {
            int m = m0 + wm + i * 16 + fq * 4 + r;
            float bb = cb[m];
            float* op = out + ((size_t)b * 256 + m) * len_out + t0;
#pragma unroll
            for (int j = 0; j < 4; ++j)
                op[wn + j * 16 + fr] = acc[i][j][r] + bb;
        }
    }
}

// ---------------------------------------------------------------------------
// MFMA flash attention (unchanged from round 3).
__global__ __launch_bounds__(256) void maeeg_fattn_kernel(
    const u16* __restrict__ Qb, const u16* __restrict__ Kb,
    const u16* __restrict__ Vt, u16* __restrict__ att)
{
    __shared__ u16 Ks[64 * 32];
    __shared__ u16 Vs[32 * 64];
    __shared__ u16 Ps[4][32 * 64];
    const int qt = blockIdx.x, h = blockIdx.y, b = blockIdx.z;
    const int t = threadIdx.x, w = t >> 6, lane = t & 63;
    const int fr = lane & 15, fq = lane >> 4;
    const u16* qbase = Qb + (size_t)b * 512 * 256 + h * 32;
    const u16* kbase = Kb + (size_t)b * 512 * 256 + h * 32;
    const u16* vbase = Vt + (size_t)b * 256 * 512 + (size_t)h * 32 * 512;

    bf16x8 qf[2];
#pragma unroll
    for (int mi = 0; mi < 2; ++mi)
        qf[mi] = *(const bf16x8*)(qbase +
                 (size_t)(qt * 128 + w * 32 + mi * 16 + fr) * 256 + fq * 8);

    f32x4 oacc[2][2];
    const f32x4 zero = {0.f, 0.f, 0.f, 0.f};
    oacc[0][0] = zero; oacc[0][1] = zero; oacc[1][0] = zero; oacc[1][1] = zero;
    float mrun[8], lrun[8];
#pragma unroll
    for (int i = 0; i < 8; ++i) { mrun[i] = -1e30f; lrun[i] = 0.f; }

    for (int kt = 0; kt < 512; kt += 64) {
        {
            int row = t >> 2, c = t & 3;
            uint4 kv = *(const uint4*)(kbase + (size_t)(kt + row) * 256 + c * 8);
            *(uint4*)((char*)Ks + row * 64 + (((c ^ (row & 3)) << 4))) = kv;
            int d = t >> 3, c2 = t & 7;
            uint4 vv = *(const uint4*)(vbase + (size_t)d * 512 + kt + c2 * 8);
            *(uint4*)((char*)Vs + d * 128 + ((c2 ^ (d & 7)) << 4)) = vv;
        }
        __syncthreads();

        f32x4 sacc[2][4];
#pragma unroll
        for (int mi = 0; mi < 2; ++mi)
#pragma unroll
            for (int ni = 0; ni < 4; ++ni) sacc[mi][ni] = zero;
        bf16x8 kf[4];
#pragma unroll
        for (int ni = 0; ni < 4; ++ni) {
            int kk = ni * 16 + fr;
            kf[ni] = *(const bf16x8*)((const char*)Ks + kk * 64 +
                                      ((fq ^ (kk & 3)) << 4));
        }
#pragma unroll
        for (int mi = 0; mi < 2; ++mi)
#pragma unroll
            for (int ni = 0; ni < 4; ++ni)
                sacc[mi][ni] = __builtin_amdgcn_mfma_f32_16x16x32_bf16(
                    qf[mi], kf[ni], sacc[mi][ni], 0, 0, 0);

#pragma unroll
        for (int mi = 0; mi < 2; ++mi) {
#pragma unroll
            for (int reg = 0; reg < 4; ++reg) {
                int idx = mi * 4 + reg;
                float rm = fmaxf(fmaxf(sacc[mi][0][reg], sacc[mi][1][reg]),
                                 fmaxf(sacc[mi][2][reg], sacc[mi][3][reg]));
                rm = fmaxf(rm, __shfl_xor(rm, 1));
                rm = fmaxf(rm, __shfl_xor(rm, 2));
                rm = fmaxf(rm, __shfl_xor(rm, 4));
                rm = fmaxf(rm, __shfl_xor(rm, 8));
                float mold = mrun[idx];
                float mnew = fmaxf(mold, rm);
                float c = __expf(mold - mnew);
                mrun[idx] = mnew;
                int q = mi * 16 + fq * 4 + reg;
                float psum = 0.f;
#pragma unroll
                for (int ni = 0; ni < 4; ++ni) {
                    float p = __expf(sacc[mi][ni][reg] - mnew);
                    psum += p;
                    int kk = ni * 16 + fr;
                    int boff = q * 128 + ((((kk >> 3) ^ (q & 7)) << 4) | ((kk & 7) << 1));
                    *(u16*)((char*)Ps[w] + boff) = f2bf(p);
                }
                lrun[idx] = lrun[idx] * c + psum;
                oacc[mi][0][reg] *= c;
                oacc[mi][1][reg] *= c;
            }
        }

        bf16x8 pf[2][2], vf[2][2];
#pragma unroll
        for (int mi = 0; mi < 2; ++mi)
#pragma unroll
            for (int kc = 0; kc < 2; ++kc) {
                int q = mi * 16 + fr;
                int ch = (kc * 4 + fq) ^ (q & 7);
                pf[mi][kc] = *(const bf16x8*)((const char*)Ps[w] + q * 128 + (ch << 4));
            }
#pragma unroll
        for (int nj = 0; nj < 2; ++nj)
#pragma unroll
            for (int kc = 0; kc < 2; ++kc) {
                int d = nj * 16 + fr;
                int ch = (kc * 4 + fq) ^ (d & 7);
                vf[nj][kc] = *(const bf16x8*)((const char*)Vs + d * 128 + (ch << 4));
            }
#pragma unroll
        for (int mi = 0; mi < 2; ++mi)
#pragma unroll
            for (int nj = 0; nj < 2; ++nj) {
                oacc[mi][nj] = __builtin_amdgcn_mfma_f32_16x16x32_bf16(
                    pf[mi][0], vf[nj][0], oacc[mi][nj], 0, 0, 0);
                oacc[mi][nj] = __builtin_amdgcn_mfma_f32_16x16x32_bf16(
                    pf[mi][1], vf[nj][1], oacc[mi][nj], 0, 0, 0);
            }
        __syncthreads();
    }

#pragma unroll
    for (int idx = 0; idx < 8; ++idx) {
        float l = lrun[idx];
        l += __shfl_xor(l, 1);
        l += __shfl_xor(l, 2);
        l += __shfl_xor(l, 4);
        l += __shfl_xor(l, 8);
        lrun[idx] = 1.f / l;
    }
    u16* ob = att + (size_t)b * 512 * 256 + h * 32;
#pragma unroll
    for (int mi = 0; mi < 2; ++mi)
#pragma unroll
        for (int reg = 0; reg < 4; ++reg) {
            int q = qt * 128 + w * 32 + mi * 16 + fq * 4 + reg;
            float inv = lrun[mi * 4 + reg];
#pragma unroll
            for (int nj = 0; nj < 2; ++nj)
                ob[(size_t)q * 256 + nj * 16 + fr] =
                    f2bf(oacc[mi][nj][reg] * inv);
        }
}

// ---------------------------------------------------------------------------
__global__ void maeeg_prep_convw_kernel(const float* __restrict__ src,
                                        u16* __restrict__ dst, int n)
{
    int i = blockIdx.x * 256 + threadIdx.x;
    if (i >= n) return;
    int r = i & 15, base = i >> 4;
    dst[i] = (r < 15) ? f2bf(src[(size_t)base * 15 + r]) : (u16)0;
}

__global__ void maeeg_cast_kernel(const float* __restrict__ src,
                                  u16* __restrict__ dst, int n)
{
    int i = blockIdx.x * 256 + threadIdx.x;
    if (i < n) dst[i] = f2bf(src[i]);
}

// pack Wq/Wk/Wv [L][65536] into WQKV [L][3][65536] at segment seg
__global__ void maeeg_cast_qkv_kernel(const float* __restrict__ src,
                                      u16* __restrict__ dst, int seg)
{
    int i = blockIdx.x * 256 + threadIdx.x;  // 0..262143
    int l = i >> 16, r = i & 65535;
    dst[(size_t)l * 196608 + seg * 65536 + r] = f2bf(src[i]);
}

__global__ void maeeg_cast_pad_kernel(const float* __restrict__ src,
                                      u16* __restrict__ dst, int len)
{
    int lip = len + 16;
    int p = blockIdx.x * 256 + threadIdx.x;
    int row = blockIdx.y;
    if (p >= lip) return;
    int q = p - 7;
    dst[(size_t)row * lip + p] =
        (q >= 0 && q < len) ? f2bf(src[(size_t)row * len + q]) : (u16)0;
}

// sinusoidal PE table [512][256]
__global__ void maeeg_pe_kernel(float* __restrict__ pet)
{
    int s = blockIdx.x, e = threadIdx.x;
    float ang = (float)s / powf(10000.f, (float)e * (1.f / 256.f));
    pet[s * 256 + e] = (e & 1) ? cosf(ang) : sinf(ang);
}

// ---------------------------------------------------------------------------
__global__ __launch_bounds__(256) void maeeg_gn_gelu_kernel(
    float* __restrict__ h, const float* __restrict__ g,
    const float* __restrict__ bta, int len, u16* __restrict__ bfout, int lip)
{
    const int grp = blockIdx.x, b = blockIdx.y;
    float* p = h + ((size_t)b * 256 + grp * 2) * len;
    const int n = 2 * len;
    float s1 = 0.f, s2 = 0.f;
    for (int i = threadIdx.x; i < n; i += 256) {
        float v = p[i];
        s1 += v; s2 += v * v;
    }
    __shared__ float sc[4];
    float S1 = maeeg_block_sum(s1, sc);
    float S2 = maeeg_block_sum(s2, sc);
    float mu = S1 / (float)n;
    float var = fmaxf(S2 / (float)n - mu * mu, 0.f);
    float rs = rsqrtf(var + 1e-5f);
    float g0 = g[grp * 2], g1 = g[grp * 2 + 1];
    float b0 = bta[grp * 2], b1 = bta[grp * 2 + 1];
    u16* bp = bfout ? bfout + ((size_t)b * 256 + grp * 2) * lip : (u16*)0;
    for (int i = threadIdx.x; i < n; i += 256) {
        float v = (p[i] - mu) * rs;
        float y = (i < len) ? (v * g0 + b0) : (v * g1 + b1);
        float ge = 0.5f * y * (1.f + erff(y * 0.70710678118654752f));
        p[i] = ge;
        if (bp) bp[(i < len ? i : (i - len) + lip) + 7] = f2bf(ge);
    }
    if (bp && threadIdx.x < 32) {
        int ch = threadIdx.x >> 4, pp = threadIdx.x & 15;
        bp[(size_t)ch * lip + ((pp < 7) ? pp : (len + pp))] = 0;
    }
}

// ---------------------------------------------------------------------------
// transpose [B,256,512] -> [B,512,256], add PE from table; fp32 + bf16.
__global__ __launch_bounds__(256) void maeeg_transpose_pos_kernel(
    const float* __restrict__ in, const float* __restrict__ pet,
    float* __restrict__ out, u16* __restrict__ outb)
{
    __shared__ float tile[256][33];
    const int s0 = blockIdx.x * 32, b = blockIdx.y;
    for (int idx = threadIdx.x; idx < 256 * 32; idx += 256) {
        int e = idx >> 5, j = idx & 31;
        tile[e][j] = in[((size_t)b * 256 + e) * 512 + s0 + j];
    }
    __syncthreads();
    for (int idx = threadIdx.x; idx < 32 * 256; idx += 256) {
        int j = idx >> 8, e = idx & 255;
        float v = tile[e][j] + pet[(s0 + j) * 256 + e];
        size_t o = ((size_t)b * 512 + s0 + j) * 256 + e;
        out[o] = v;
        outb[o] = f2bf(v);
    }
}

// ---------------------------------------------------------------------------
__global__ __launch_bounds__(256) void maeeg_ln_kernel(
    const float* __restrict__ in, float* __restrict__ out,
    u16* __restrict__ bfout, const float* __restrict__ g,
    const float* __restrict__ b)
{
    const int m = blockIdx.x, t = threadIdx.x;
    float x = in[(size_t)m * 256 + t];
    __shared__ float sc[4];
    float mu = maeeg_block_sum(x, sc) * (1.f / 256.f);
    float d = x - mu;
    float var = maeeg_block_sum(d * d, sc) * (1.f / 256.f);
    float v = d * rsqrtf(var + 1e-5f) * g[t] + b[t];
    out[(size_t)m * 256 + t] = v;
    bfout[(size_t)m * 256 + t] = f2bf(v);
}

// ---------------------------------------------------------------------------
// classifier stage 1: MFMA split-K. flatb bf16 [32][131072] (= Cb), Wc1 fp32
// converted inline to bf16. part[ks][32][256]. grid (128 ks, 4 jt), 256 thr.
__global__ __launch_bounds__(256) void maeeg_cls1_kernel(
    const u16* __restrict__ flatb, const float* __restrict__ Wc1,
    float* __restrict__ part)
{
    __shared__ u16 As[32 * 64];   // [32 m][64 k], 128B rows, swizzled
    __shared__ u16 Bs[64 * 64];   // [64 j][64 k]
    const int ks = blockIdx.x, jt = blockIdx.y;
    const int t = threadIdx.x, w = t >> 6, lane = t & 63;
    const int fr = lane & 15, fq = lane >> 4;
    const int kbase0 = ks * 1024;
    const int arow = t >> 3, ac = t & 7;   // A stage map
    const int brow = t >> 2, bq = t & 3;   // B stage map

    f32x4 acc[2];
    const f32x4 zero = {0.f, 0.f, 0.f, 0.f};
    acc[0] = zero; acc[1] = zero;

    for (int step = 0; step < 16; ++step) {
        int kk = kbase0 + step * 64;
        // A: 32 x 64 bf16 (flat)
        uint4 va = *(const uint4*)(flatb + (size_t)arow * 131072 + kk + ac * 8);
        *(uint4*)((char*)As + arow * 128 + ((ac ^ (arow & 7)) << 4)) = va;
        // B: 64 x 64, fp32 -> bf16 inline (each thread converts 16 floats)
        const float* wp = Wc1 + (size_t)(jt * 64 + brow) * 131072 + kk + bq * 16;
        float4 f0 = ((const float4*)wp)[0];
        float4 f1 = ((const float4*)wp)[1];
        float4 f2 = ((const float4*)wp)[2];
        float4 f3 = ((const float4*)wp)[3];
        uint4 p0, p1;
        p0.x = (u32)f2bf(f0.x) | ((u32)f2bf(f0.y) << 16);
        p0.y = (u32)f2bf(f0.z) | ((u32)f2bf(f0.w) << 16);
        p0.z = (u32)f2bf(f1.x) | ((u32)f2bf(f1.y) << 16);
        p0.w = (u32)f2bf(f1.z) | ((u32)f2bf(f1.w) << 16);
        p1.x = (u32)f2bf(f2.x) | ((u32)f2bf(f2.y) << 16);
        p1.y = (u32)f2bf(f2.z) | ((u32)f2bf(f2.w) << 16);
        p1.z = (u32)f2bf(f3.x) | ((u32)f2bf(f3.y) << 16);
        p1.w = (u32)f2bf(f3.z) | ((u32)f2bf(f3.w) << 16);
        int c0 = bq * 2, c1 = bq * 2 + 1;
        *(uint4*)((char*)Bs + brow * 128 + ((c0 ^ (brow & 7)) << 4)) = p0;
        *(uint4*)((char*)Bs + brow * 128 + ((c1 ^ (brow & 7)) << 4)) = p1;
        __syncthreads();
#pragma unroll
        for (int kc = 0; kc < 2; ++kc) {
            int kbyte = kc * 64 + fq * 16;
            int bn = w * 16 + fr;
            bf16x8 bfv = *(const bf16x8*)((const char*)Bs + bn * 128 +
                                          (kbyte ^ ((bn & 7) << 4)));
#pragma unroll
            for (int mi = 0; mi < 2; ++mi) {
                int am = mi * 16 + fr;
                bf16x8 af = *(const bf16x8*)((const char*)As + am * 128 +
                                             (kbyte ^ ((am & 7) << 4)));
                acc[mi] = __builtin_amdgcn_mfma_f32_16x16x32_bf16(
                    af, bfv, acc[mi], 0, 0, 0);
            }
        }
        __syncthreads();
    }
#pragma unroll
    for (int mi = 0; mi < 2; ++mi)
#pragma unroll
        for (int r = 0; r < 4; ++r) {
            int m = mi * 16 + fq * 4 + r;
            int j = jt * 64 + w * 16 + fr;
            part[((size_t)ks * 32 + m) * 256 + j] = acc[mi][r];
        }
}

__global__ void maeeg_cls2_kernel(const float* __restrict__ part,
                                  const float* __restrict__ bc1,
                                  float* __restrict__ hid)
{
    const int b = blockIdx.x, j = threadIdx.x;
    float s = bc1[j];
    for (int ks = 0; ks < 128; ++ks) s += part[((size_t)ks * 32 + b) * 256 + j];
    hid[b * 256 + j] = fmaxf(s, 0.f);
}

__global__ void maeeg_cls3_kernel(const float* __restrict__ hid,
                                  const float* __restrict__ Wc2,
                                  const float* __restrict__ bc2,
                                  float* __restrict__ out)
{
    const int b = blockIdx.x, t = threadIdx.x;
    float v = hid[b * 256 + t] * Wc2[t];
#pragma unroll
    for (int off = 32; off; off >>= 1) v += __shfl_down(v, off);
    __shared__ float r[4];
    if ((t & 63) == 0) r[t >> 6] = v;
    __syncthreads();
    if (t == 0) {
        float s = r[0] + r[1] + r[2] + r[3] + bc2[0];
        out[b] = 1.f / (1.f + expf(-s));
    }
}

// ===========================================================================
extern "C" void kernel_launch(void* const* d_in, const int* in_sizes, int n_in,
                              void* d_out, int out_size, void* d_ws, size_t ws_size,
                              hipStream_t stream)
{
    (void)in_sizes; (void)n_in; (void)out_size; (void)ws_size;
    const float* x        = (const float*)d_in[0];
    const float* conv0_w  = (const float*)d_in[1];
    const float* conv0_b  = (const float*)d_in[2];
    const float* conv12_w = (const float*)d_in[3];
    const float* conv12_b = (const float*)d_in[4];
    const float* gn_g     = (const float*)d_in[5];
    const float* gn_b     = (const float*)d_in[6];
    const float* Wq       = (const float*)d_in[7];
    const float* Wk       = (const float*)d_in[8];
    const float* Wv       = (const float*)d_in[9];
    const float* Wo       = (const float*)d_in[10];
    const float* ln1_g    = (const float*)d_in[11];
    const float* ln1_b    = (const float*)d_in[12];
    const float* Wf1      = (const float*)d_in[13];
    const float* bf1      = (const float*)d_in[14];
    const float* Wf2      = (const float*)d_in[15];
    const float* bf2      = (const float*)d_in[16];
    const float* ln2_g    = (const float*)d_in[17];
    const float* ln2_b    = (const float*)d_in[18];
    const float* Wc1      = (const float*)d_in[19];
    const float* bc1      = (const float*)d_in[20];
    const float* Wc2      = (const float*)d_in[21];
    const float* bc2      = (const float*)d_in[22];
    float* out = (float*)d_out;

    // ---- workspace layout (bytes) ----
    char* wsb = (char*)d_ws;
    u16* WB0   = (u16*)(wsb + 0);          //   524,288
    u16* WB12  = (u16*)(wsb + 524288);     // 4,194,304
    u16* WQKVb = (u16*)(wsb + 4718592);    // 1,572,864 [L][3][256][256]
    u16* WOb   = (u16*)(wsb + 6291456);    //   524,288
    u16* WF1b  = (u16*)(wsb + 6815744);    // 2,097,152
    u16* WF2b  = (u16*)(wsb + 8912896);    // 2,097,152 -> 11,010,048
    // R1: XPAD -> GN1B -> D
    u16*   XPAD  = (u16*)(wsb + 11010048);
    u16*   GN1B  = (u16*)(wsb + 11010048);
    float* D     = (float*)(wsb + 11010048);
    // R2 (67,108,864): CONV0 -> CONV1/CONV2 -> QKV/ATT/Db -> F1b
    float* CONV0 = (float*)(wsb + 28049408);
    float* CONV1 = (float*)(wsb + 28049408);
    float* CONV2 = (float*)(wsb + 28049408 + 33554432);
    u16*   Qb2   = (u16*)(wsb + 28049408);              // +0 (QKV packed base)
    u16*   ATTb  = (u16*)(wsb + 28049408 + 25165824);
    u16*   Db    = (u16*)(wsb + 28049408 + 33554432);
    u16*   F1b   = (u16*)(wsb + 28049408);
    // R3: GN0B -> C + Cb
    u16*   GN0B  = (u16*)(wsb + 95158272);
    float* C     = (float*)(wsb + 95158272);
    u16*   Cb    = (u16*)(wsb + 95158272 + 16777216);   // == flat bf16
    // R4
    float* PART  = (float*)(wsb + 128974848);           // 4,194,304
    float* HID   = (float*)(wsb + 133169152);           //    32,768
    float* PET   = (float*)(wsb + 133201920);           //   524,288

    // ---- weight prep ----
    maeeg_prep_convw_kernel<<<1024, 256, 0, stream>>>(conv0_w, WB0, 262144);
    maeeg_prep_convw_kernel<<<8192, 256, 0, stream>>>(conv12_w, WB12, 2097152);
    maeeg_cast_qkv_kernel<<<1024, 256, 0, stream>>>(Wq, WQKVb, 0);
    maeeg_cast_qkv_kernel<<<1024, 256, 0, stream>>>(Wk, WQKVb, 1);
    maeeg_cast_qkv_kernel<<<1024, 256, 0, stream>>>(Wv, WQKVb, 2);
    maeeg_cast_kernel<<<1024, 256, 0, stream>>>(Wo, WOb, 262144);
    maeeg_cast_kernel<<<4096, 256, 0, stream>>>(Wf1, WF1b, 1048576);
    maeeg_cast_kernel<<<4096, 256, 0, stream>>>(Wf2, WF2b, 1048576);
    maeeg_cast_pad_kernel<<<dim3(17, 2048), 256, 0, stream>>>(x, XPAD, 4096);
    maeeg_pe_kernel<<<512, 256, 0, stream>>>(PET);

    // ---- conv encoder ----
    maeeg_convmm_kernel<<<dim3(2, 16, 32), 256, 0, stream>>>(
        WB0, XPAD, conv0_b, CONV0, 1024, 4096, 2048);
    maeeg_gn_gelu_kernel<<<dim3(128, 32), 256, 0, stream>>>(
        CONV0, gn_g, gn_b, 2048, GN0B, 2064);
    maeeg_convmm_kernel<<<dim3(2, 8, 32), 256, 0, stream>>>(
        WB12, GN0B, conv12_b, CONV1, 4096, 2048, 1024);
    maeeg_gn_gelu_kernel<<<dim3(128, 32), 256, 0, stream>>>(
        CONV1, gn_g + 256, gn_b + 256, 1024, GN1B, 1040);
    maeeg_convmm_kernel<<<dim3(2, 4, 32), 256, 0, stream>>>(
        WB12 + 256 * 4096, GN1B, conv12_b + 256, CONV2, 4096, 1024, 512);
    maeeg_gn_gelu_kernel<<<dim3(128, 32), 256, 0, stream>>>(
        CONV2, gn_g + 512, gn_b + 512, 512, (u16*)0, 0);
    maeeg_transpose_pos_kernel<<<dim3(16, 32), 256, 0, stream>>>(CONV2, PET, C, Cb);

    // ---- transformer encoder ----
    for (int l = 0; l < 4; ++l) {
        maeeg_mm_kernel<<<dim3(128, 6), 256, 0, stream>>>(
            Cb, WQKVb + l * 196608, (const float*)0, (const float*)0,
            Qb2, 256, 256, 16);
        maeeg_fattn_kernel<<<dim3(4, 8, 32), 256, 0, stream>>>(
            Qb2, Qb2 + 4194304, Qb2 + 8388608, ATTb);
        maeeg_mm_kernel<<<dim3(128, 2), 256, 0, stream>>>(
            ATTb, WOb + l * 65536, (const float*)0, C, D, 256, 256, 0);
        maeeg_ln_kernel<<<16384, 256, 0, stream>>>(
            D, D, Db, ln1_g + l * 256, ln1_b + l * 256);
        maeeg_mm_kernel<<<dim3(128, 8), 256, 0, stream>>>(
            Db, WF1b + l * 262144, bf1 + l * 1024, (const float*)0, F1b, 1024, 256, 3);
        maeeg_mm_kernel<<<dim3(128, 2), 256, 0, stream>>>(
            F1b, WF2b + l * 262144, bf2 + l * 256, D, C, 256, 1024, 0);
        maeeg_ln_kernel<<<16384, 256, 0, stream>>>(
            C, C, Cb, ln2_g + l * 256, ln2_b + l * 256);
    }

    // ---- classifier ----
    maeeg_cls1_kernel<<<dim3(128, 4), 256, 0, stream>>>(Cb, Wc1, PART);
    maeeg_cls2_kernel<<<32, 256, 0, stream>>>(PART, bc1, HID);
    maeeg_cls3_kernel<<<32, 256, 0, stream>>>(HID, Wc2, bc2, out);
}

// Round 6
// 1304.232 us; speedup vs baseline: 4.9159x; 1.0012x over previous
//
#include <hip/hip_runtime.h>
#include <math.h>

// ============================================================================
// MAEEG classification, round 4:
//   - cls1 rewritten as MFMA split-K GEMM with INLINE fp32->bf16 conversion of
//     Wc1 (single HBM pass over the 134MB weight, no separate cast kernel);
//     flat operand = Cb (bf16 shadow of final LN) which IS flat[32][131072].
//     grid (128 ks, 4 jt), 12KB LDS, 2 blocks/CU.
//   - QKV projections fused into ONE mm dispatch (N=768, packed weights);
//     epilogue routes seg0->Q(scaled), seg1->K, seg2->V-transposed.
//   - sinusoidal PE hoisted to a one-time [512][256] table.
//   - everything else as round 3 (MFMA convs, MFMA flash attention, fp32
//     master activation path with fused bf16 shadows).
// ============================================================================

typedef unsigned int   u32;
typedef unsigned short u16;
typedef __attribute__((ext_vector_type(4))) float f32x4;
typedef __attribute__((ext_vector_type(8))) short bf16x8;

__device__ __forceinline__ u16 f2bf(float v) {
    union { float f; u32 u; } x; x.f = v;
    u32 r = x.u + 0x7fffu + ((x.u >> 16) & 1u);  // RNE
    return (u16)(r >> 16);
}

// ---------------------------------------------------------------------------
__device__ __forceinline__ float maeeg_block_sum(float v, float* sc4) {
#pragma unroll
    for (int off = 32; off; off >>= 1) v += __shfl_down(v, off);
    int t = threadIdx.x;
    if ((t & 63) == 0) sc4[t >> 6] = v;
    __syncthreads();
    float r = sc4[0] + sc4[1] + sc4[2] + sc4[3];
    __syncthreads();
    return r;
}

// ---------------------------------------------------------------------------
// bf16 MFMA GEMM: out[m][n] = sum_k A[m][k]*B[n][k] (+bias[n]) (+res)
// flags: 1 relu | 2 bf16 out | 4 transposed bf16 out | 16 fused-QKV routing
__global__ __launch_bounds__(256) void maeeg_mm_kernel(
    const u16* __restrict__ Ag, const u16* __restrict__ Bg,
    const float* __restrict__ bias, const float* __restrict__ res,
    void* __restrict__ outp, int N, int K, int flags)
{
    __shared__ u16 As[8192];  // [128 rows][64 k] bf16, 128B/row, XOR-swizzled
    __shared__ u16 Bs[8192];
    const int m0 = blockIdx.x * 128, n0 = blockIdx.y * 128;
    const int t = threadIdx.x, w = t >> 6, lane = t & 63;
    const int sr = lane & 7, sc = lane >> 3;
    const int fr = lane & 15, fq = lane >> 4;
    const int wm = (w >> 1) * 64, wn = (w & 1) * 64;

    f32x4 acc[4][4];
    const f32x4 zero = {0.f, 0.f, 0.f, 0.f};
#pragma unroll
    for (int i = 0; i < 4; ++i)
#pragma unroll
        for (int j = 0; j < 4; ++j) acc[i][j] = zero;

    for (int k0 = 0; k0 < K; k0 += 64) {
#pragma unroll
        for (int j = 0; j < 4; ++j) {
            int row = w * 32 + j * 8 + sr;
            uint4 va = *(const uint4*)(Ag + (size_t)(m0 + row) * K + k0 + sc * 8);
            uint4 vb = *(const uint4*)(Bg + (size_t)(n0 + row) * K + k0 + sc * 8);
            int kb = (sc ^ (row & 7)) << 4;
            *(uint4*)((char*)As + row * 128 + kb) = va;
            *(uint4*)((char*)Bs + row * 128 + kb) = vb;
        }
        __syncthreads();
#pragma unroll
        for (int kc = 0; kc < 2; ++kc) {
            bf16x8 af[4], bfv[4];
#pragma unroll
            for (int i = 0; i < 4; ++i) {
                int am = wm + i * 16 + fr;
                int bn = wn + i * 16 + fr;
                int kb = kc * 64 + fq * 16;
                af[i]  = *(const bf16x8*)((const char*)As + am * 128 + (kb ^ ((am & 7) << 4)));
                bfv[i] = *(const bf16x8*)((const char*)Bs + bn * 128 + (kb ^ ((bn & 7) << 4)));
            }
#pragma unroll
            for (int i = 0; i < 4; ++i)
#pragma unroll
                for (int j = 0; j < 4; ++j)
                    acc[i][j] = __builtin_amdgcn_mfma_f32_16x16x32_bf16(
                        af[i], bfv[j], acc[i][j], 0, 0, 0);
        }
        __syncthreads();
    }
#pragma unroll
    for (int i = 0; i < 4; ++i) {
#pragma unroll
        for (int j = 0; j < 4; ++j) {
            int n = n0 + wn + j * 16 + fr;
            float bv = bias ? bias[n] : 0.f;
#pragma unroll
            for (int r = 0; r < 4; ++r) {
                int m = m0 + wm + i * 16 + fq * 4 + r;
                float v = acc[i][j][r] + bv;
                if (res) v += res[(size_t)m * N + n];
                if (flags & 1) v = fmaxf(v, 0.f);
                if (flags & 16) {
                    // fused QKV: seg0 -> Q (scaled), seg1 -> K, seg2 -> V^T
                    u16* o = (u16*)outp;
                    int seg = n >> 8, nn = n & 255;
                    if (seg == 0)
                        o[(size_t)m * 256 + nn] = f2bf(v * 0.17677669529663687f);
                    else if (seg == 1)
                        o[4194304 + (size_t)m * 256 + nn] = f2bf(v);
                    else
                        o[8388608 + (((size_t)(m >> 9)) * 256 + nn) * 512 + (m & 511)] = f2bf(v);
                } else if (flags & 4)
                    ((u16*)outp)[(((size_t)(m >> 9)) * 256 + n) * 512 + (m & 511)] = f2bf(v);
                else if (flags & 2)
                    ((u16*)outp)[(size_t)m * N + n] = f2bf(v);
                else
                    ((float*)outp)[(size_t)m * N + n] = v;
            }
        }
    }
}

// ---------------------------------------------------------------------------
// bf16 MFMA implicit-GEMM conv1d (stride 2, taps 15 padded to 16).
__global__ __launch_bounds__(256) void maeeg_convmm_kernel(
    const u16* __restrict__ Wp, const u16* __restrict__ inp,
    const float* __restrict__ cb, float* __restrict__ out,
    int K3, int len_in, int len_out)
{
    __shared__ u16 As[8192];
    __shared__ u16 Bs[8192];
    const int m0 = blockIdx.x * 128, t0 = blockIdx.y * 128, b = blockIdx.z;
    const int lip = len_in + 16;
    const u16* inb = inp + (size_t)b * (K3 >> 4) * lip;
    const int t = threadIdx.x, w = t >> 6, lane = t & 63;
    const int sr = lane & 7, sc = lane >> 3;
    const int fr = lane & 15, fq = lane >> 4;
    const int wm = (w >> 1) * 64, wn = (w & 1) * 64;

    f32x4 acc[4][4];
    const f32x4 zero = {0.f, 0.f, 0.f, 0.f};
#pragma unroll
    for (int i = 0; i < 4; ++i)
#pragma unroll
        for (int j = 0; j < 4; ++j) acc[i][j] = zero;

    for (int k0 = 0; k0 < K3; k0 += 64) {
#pragma unroll
        for (int j = 0; j < 4; ++j) {
            int row = w * 32 + j * 8 + sr;
            uint4 va = *(const uint4*)(Wp + (size_t)(m0 + row) * K3 + k0 + sc * 8);
            int k  = k0 + sc * 8;
            int ci = k >> 4, rr = k & 15;
            int tg = t0 + row;
            const u16* gp = inb + (size_t)ci * lip + 2 * tg + rr;
            uint4 vb;
            vb.x = *(const u32*)(gp);
            vb.y = *(const u32*)(gp + 2);
            vb.z = *(const u32*)(gp + 4);
            vb.w = *(const u32*)(gp + 6);
            int kb = (sc ^ (row & 7)) << 4;
            *(uint4*)((char*)As + row * 128 + kb) = va;
            *(uint4*)((char*)Bs + row * 128 + kb) = vb;
        }
        __syncthreads();
#pragma unroll
        for (int kc = 0; kc < 2; ++kc) {
            bf16x8 af[4], bfv[4];
#pragma unroll
            for (int i = 0; i < 4; ++i) {
                int am = wm + i * 16 + fr;
                int bn = wn + i * 16 + fr;
                int kb = kc * 64 + fq * 16;
                af[i]  = *(const bf16x8*)((const char*)As + am * 128 + (kb ^ ((am & 7) << 4)));
                bfv[i] = *(const bf16x8*)((const char*)Bs + bn * 128 + (kb ^ ((bn & 7) << 4)));
            }
#pragma unroll
            for (int i = 0; i < 4; ++i)
#pragma unroll
                for (int j = 0; j < 4; ++j)
                    acc[i][j] = __builtin_amdgcn_mfma_f32_16x16x32_bf16(
                        af[i], bfv[j], acc[i][j], 0, 0, 0);
        }
        __syncthreads();
    }
#pragma unroll
    for (int i = 0; i < 4; ++i) {
#pragma unroll
        for (int r = 0; r < 4; ++r) {
            int m = m0 + wm + i * 16 + fq * 4 + r;
            float bb = cb[m];
            float* op = out + ((size_t)b * 256 + m) * len_out + t0;
#pragma unroll
            for (int j = 0; j < 4; ++j)
                op[wn + j * 16 + fr] = acc[i][j][r] + bb;
        }
    }
}

// ---------------------------------------------------------------------------
// MFMA flash attention (unchanged from round 3).
__global__ __launch_bounds__(256) void maeeg_fattn_kernel(
    const u16* __restrict__ Qb, const u16* __restrict__ Kb,
    const u16* __restrict__ Vt, u16* __restrict__ att)
{
    __shared__ u16 Ks[64 * 32];
    __shared__ u16 Vs[32 * 64];
    __shared__ u16 Ps[4][32 * 64];
    const int qt = blockIdx.x, h = blockIdx.y, b = blockIdx.z;
    const int t = threadIdx.x, w = t >> 6, lane = t & 63;
    const int fr = lane & 15, fq = lane >> 4;
    const u16* qbase = Qb + (size_t)b * 512 * 256 + h * 32;
    const u16* kbase = Kb + (size_t)b * 512 * 256 + h * 32;
    const u16* vbase = Vt + (size_t)b * 256 * 512 + (size_t)h * 32 * 512;

    bf16x8 qf[2];
#pragma unroll
    for (int mi = 0; mi < 2; ++mi)
        qf[mi] = *(const bf16x8*)(qbase +
                 (size_t)(qt * 128 + w * 32 + mi * 16 + fr) * 256 + fq * 8);

    f32x4 oacc[2][2];
    const f32x4 zero = {0.f, 0.f, 0.f, 0.f};
    oacc[0][0] = zero; oacc[0][1] = zero; oacc[1][0] = zero; oacc[1][1] = zero;
    float mrun[8], lrun[8];
#pragma unroll
    for (int i = 0; i < 8; ++i) { mrun[i] = -1e30f; lrun[i] = 0.f; }

    for (int kt = 0; kt < 512; kt += 64) {
        {
            int row = t >> 2, c = t & 3;
            uint4 kv = *(const uint4*)(kbase + (size_t)(kt + row) * 256 + c * 8);
            *(uint4*)((char*)Ks + row * 64 + (((c ^ (row & 3)) << 4))) = kv;
            int d = t >> 3, c2 = t & 7;
            uint4 vv = *(const uint4*)(vbase + (size_t)d * 512 + kt + c2 * 8);
            *(uint4*)((char*)Vs + d * 128 + ((c2 ^ (d & 7)) << 4)) = vv;
        }
        __syncthreads();

        f32x4 sacc[2][4];
#pragma unroll
        for (int mi = 0; mi < 2; ++mi)
#pragma unroll
            for (int ni = 0; ni < 4; ++ni) sacc[mi][ni] = zero;
        bf16x8 kf[4];
#pragma unroll
        for (int ni = 0; ni < 4; ++ni) {
            int kk = ni * 16 + fr;
            kf[ni] = *(const bf16x8*)((const char*)Ks + kk * 64 +
                                      ((fq ^ (kk & 3)) << 4));
        }
#pragma unroll
        for (int mi = 0; mi < 2; ++mi)
#pragma unroll
            for (int ni = 0; ni < 4; ++ni)
                sacc[mi][ni] = __builtin_amdgcn_mfma_f32_16x16x32_bf16(
                    qf[mi], kf[ni], sacc[mi][ni], 0, 0, 0);

#pragma unroll
        for (int mi = 0; mi < 2; ++mi) {
#pragma unroll
            for (int reg = 0; reg < 4; ++reg) {
                int idx = mi * 4 + reg;
                float rm = fmaxf(fmaxf(sacc[mi][0][reg], sacc[mi][1][reg]),
                                 fmaxf(sacc[mi][2][reg], sacc[mi][3][reg]));
                rm = fmaxf(rm, __shfl_xor(rm, 1));
                rm = fmaxf(rm, __shfl_xor(rm, 2));
                rm = fmaxf(rm, __shfl_xor(rm, 4));
                rm = fmaxf(rm, __shfl_xor(rm, 8));
                float mold = mrun[idx];
                float mnew = fmaxf(mold, rm);
                float c = __expf(mold - mnew);
                mrun[idx] = mnew;
                int q = mi * 16 + fq * 4 + reg;
                float psum = 0.f;
#pragma unroll
                for (int ni = 0; ni < 4; ++ni) {
                    float p = __expf(sacc[mi][ni][reg] - mnew);
                    psum += p;
                    int kk = ni * 16 + fr;
                    int boff = q * 128 + ((((kk >> 3) ^ (q & 7)) << 4) | ((kk & 7) << 1));
                    *(u16*)((char*)Ps[w] + boff) = f2bf(p);
                }
                lrun[idx] = lrun[idx] * c + psum;
                oacc[mi][0][reg] *= c;
                oacc[mi][1][reg] *= c;
            }
        }

        bf16x8 pf[2][2], vf[2][2];
#pragma unroll
        for (int mi = 0; mi < 2; ++mi)
#pragma unroll
            for (int kc = 0; kc < 2; ++kc) {
                int q = mi * 16 + fr;
                int ch = (kc * 4 + fq) ^ (q & 7);
                pf[mi][kc] = *(const bf16x8*)((const char*)Ps[w] + q * 128 + (ch << 4));
            }
#pragma unroll
        for (int nj = 0; nj < 2; ++nj)
#pragma unroll
            for (int kc = 0; kc < 2; ++kc) {
                int d = nj * 16 + fr;
                int ch = (kc * 4 + fq) ^ (d & 7);
                vf[nj][kc] = *(const bf16x8*)((const char*)Vs + d * 128 + (ch << 4));
            }
#pragma unroll
        for (int mi = 0; mi < 2; ++mi)
#pragma unroll
            for (int nj = 0; nj < 2; ++nj) {
                oacc[mi][nj] = __builtin_amdgcn_mfma_f32_16x16x32_bf16(
                    pf[mi][0], vf[nj][0], oacc[mi][nj], 0, 0, 0);
                oacc[mi][nj] = __builtin_amdgcn_mfma_f32_16x16x32_bf16(
                    pf[mi][1], vf[nj][1], oacc[mi][nj], 0, 0, 0);
            }
        __syncthreads();
    }

#pragma unroll
    for (int idx = 0; idx < 8; ++idx) {
        float l = lrun[idx];
        l += __shfl_xor(l, 1);
        l += __shfl_xor(l, 2);
        l += __shfl_xor(l, 4);
        l += __shfl_xor(l, 8);
        lrun[idx] = 1.f / l;
    }
    u16* ob = att + (size_t)b * 512 * 256 + h * 32;
#pragma unroll
    for (int mi = 0; mi < 2; ++mi)
#pragma unroll
        for (int reg = 0; reg < 4; ++reg) {
            int q = qt * 128 + w * 32 + mi * 16 + fq * 4 + reg;
            float inv = lrun[mi * 4 + reg];
#pragma unroll
            for (int nj = 0; nj < 2; ++nj)
                ob[(size_t)q * 256 + nj * 16 + fr] =
                    f2bf(oacc[mi][nj][reg] * inv);
        }
}

// ---------------------------------------------------------------------------
__global__ void maeeg_prep_convw_kernel(const float* __restrict__ src,
                                        u16* __restrict__ dst, int n)
{
    int i = blockIdx.x * 256 + threadIdx.x;
    if (i >= n) return;
    int r = i & 15, base = i >> 4;
    dst[i] = (r < 15) ? f2bf(src[(size_t)base * 15 + r]) : (u16)0;
}

__global__ void maeeg_cast_kernel(const float* __restrict__ src,
                                  u16* __restrict__ dst, int n)
{
    int i = blockIdx.x * 256 + threadIdx.x;
    if (i < n) dst[i] = f2bf(src[i]);
}

// pack Wq/Wk/Wv [L][65536] into WQKV [L][3][65536] at segment seg
__global__ void maeeg_cast_qkv_kernel(const float* __restrict__ src,
                                      u16* __restrict__ dst, int seg)
{
    int i = blockIdx.x * 256 + threadIdx.x;  // 0..262143
    int l = i >> 16, r = i & 65535;
    dst[(size_t)l * 196608 + seg * 65536 + r] = f2bf(src[i]);
}

__global__ void maeeg_cast_pad_kernel(const float* __restrict__ src,
                                      u16* __restrict__ dst, int len)
{
    int lip = len + 16;
    int p = blockIdx.x * 256 + threadIdx.x;
    int row = blockIdx.y;
    if (p >= lip) return;
    int q = p - 7;
    dst[(size_t)row * lip + p] =
        (q >= 0 && q < len) ? f2bf(src[(size_t)row * len + q]) : (u16)0;
}

// sinusoidal PE table [512][256]
__global__ void maeeg_pe_kernel(float* __restrict__ pet)
{
    int s = blockIdx.x, e = threadIdx.x;
    float ang = (float)s / powf(10000.f, (float)e * (1.f / 256.f));
    pet[s * 256 + e] = (e & 1) ? cosf(ang) : sinf(ang);
}

// ---------------------------------------------------------------------------
__global__ __launch_bounds__(256) void maeeg_gn_gelu_kernel(
    float* __restrict__ h, const float* __restrict__ g,
    const float* __restrict__ bta, int len, u16* __restrict__ bfout, int lip)
{
    const int grp = blockIdx.x, b = blockIdx.y;
    float* p = h + ((size_t)b * 256 + grp * 2) * len;
    const int n = 2 * len;
    float s1 = 0.f, s2 = 0.f;
    for (int i = threadIdx.x; i < n; i += 256) {
        float v = p[i];
        s1 += v; s2 += v * v;
    }
    __shared__ float sc[4];
    float S1 = maeeg_block_sum(s1, sc);
    float S2 = maeeg_block_sum(s2, sc);
    float mu = S1 / (float)n;
    float var = fmaxf(S2 / (float)n - mu * mu, 0.f);
    float rs = rsqrtf(var + 1e-5f);
    float g0 = g[grp * 2], g1 = g[grp * 2 + 1];
    float b0 = bta[grp * 2], b1 = bta[grp * 2 + 1];
    u16* bp = bfout ? bfout + ((size_t)b * 256 + grp * 2) * lip : (u16*)0;
    for (int i = threadIdx.x; i < n; i += 256) {
        float v = (p[i] - mu) * rs;
        float y = (i < len) ? (v * g0 + b0) : (v * g1 + b1);
        float ge = 0.5f * y * (1.f + erff(y * 0.70710678118654752f));
        p[i] = ge;
        if (bp) bp[(i < len ? i : (i - len) + lip) + 7] = f2bf(ge);
    }
    if (bp && threadIdx.x < 32) {
        int ch = threadIdx.x >> 4, pp = threadIdx.x & 15;
        bp[(size_t)ch * lip + ((pp < 7) ? pp : (len + pp))] = 0;
    }
}

// ---------------------------------------------------------------------------
// transpose [B,256,512] -> [B,512,256], add PE from table; fp32 + bf16.
__global__ __launch_bounds__(256) void maeeg_transpose_pos_kernel(
    const float* __restrict__ in, const float* __restrict__ pet,
    float* __restrict__ out, u16* __restrict__ outb)
{
    __shared__ float tile[256][33];
    const int s0 = blockIdx.x * 32, b = blockIdx.y;
    for (int idx = threadIdx.x; idx < 256 * 32; idx += 256) {
        int e = idx >> 5, j = idx & 31;
        tile[e][j] = in[((size_t)b * 256 + e) * 512 + s0 + j];
    }
    __syncthreads();
    for (int idx = threadIdx.x; idx < 32 * 256; idx += 256) {
        int j = idx >> 8, e = idx & 255;
        float v = tile[e][j] + pet[(s0 + j) * 256 + e];
        size_t o = ((size_t)b * 512 + s0 + j) * 256 + e;
        out[o] = v;
        outb[o] = f2bf(v);
    }
}

// ---------------------------------------------------------------------------
__global__ __launch_bounds__(256) void maeeg_ln_kernel(
    const float* __restrict__ in, float* __restrict__ out,
    u16* __restrict__ bfout, const float* __restrict__ g,
    const float* __restrict__ b)
{
    const int m = blockIdx.x, t = threadIdx.x;
    float x = in[(size_t)m * 256 + t];
    __shared__ float sc[4];
    float mu = maeeg_block_sum(x, sc) * (1.f / 256.f);
    float d = x - mu;
    float var = maeeg_block_sum(d * d, sc) * (1.f / 256.f);
    float v = d * rsqrtf(var + 1e-5f) * g[t] + b[t];
    out[(size_t)m * 256 + t] = v;
    bfout[(size_t)m * 256 + t] = f2bf(v);
}

// ---------------------------------------------------------------------------
// classifier stage 1: MFMA split-K. flatb bf16 [32][131072] (= Cb), Wc1 fp32
// converted inline to bf16. part[ks][32][256]. grid (128 ks, 4 jt), 256 thr.
__global__ __launch_bounds__(256) void maeeg_cls1_kernel(
    const u16* __restrict__ flatb, const float* __restrict__ Wc1,
    float* __restrict__ part)
{
    __shared__ u16 As[32 * 64];   // [32 m][64 k], 128B rows, swizzled
    __shared__ u16 Bs[64 * 64];   // [64 j][64 k]
    const int ks = blockIdx.x, jt = blockIdx.y;
    const int t = threadIdx.x, w = t >> 6, lane = t & 63;
    const int fr = lane & 15, fq = lane >> 4;
    const int kbase0 = ks * 1024;
    const int arow = t >> 3, ac = t & 7;   // A stage map
    const int brow = t >> 2, bq = t & 3;   // B stage map

    f32x4 acc[2];
    const f32x4 zero = {0.f, 0.f, 0.f, 0.f};
    acc[0] = zero; acc[1] = zero;

    for (int step = 0; step < 16; ++step) {
        int kk = kbase0 + step * 64;
        // A: 32 x 64 bf16 (flat)
        uint4 va = *(const uint4*)(flatb + (size_t)arow * 131072 + kk + ac * 8);
        *(uint4*)((char*)As + arow * 128 + ((ac ^ (arow & 7)) << 4)) = va;
        // B: 64 x 64, fp32 -> bf16 inline (each thread converts 16 floats)
        const float* wp = Wc1 + (size_t)(jt * 64 + brow) * 131072 + kk + bq * 16;
        float4 f0 = ((const float4*)wp)[0];
        float4 f1 = ((const float4*)wp)[1];
        float4 f2 = ((const float4*)wp)[2];
        float4 f3 = ((const float4*)wp)[3];
        uint4 p0, p1;
        p0.x = (u32)f2bf(f0.x) | ((u32)f2bf(f0.y) << 16);
        p0.y = (u32)f2bf(f0.z) | ((u32)f2bf(f0.w) << 16);
        p0.z = (u32)f2bf(f1.x) | ((u32)f2bf(f1.y) << 16);
        p0.w = (u32)f2bf(f1.z) | ((u32)f2bf(f1.w) << 16);
        p1.x = (u32)f2bf(f2.x) | ((u32)f2bf(f2.y) << 16);
        p1.y = (u32)f2bf(f2.z) | ((u32)f2bf(f2.w) << 16);
        p1.z = (u32)f2bf(f3.x) | ((u32)f2bf(f3.y) << 16);
        p1.w = (u32)f2bf(f3.z) | ((u32)f2bf(f3.w) << 16);
        int c0 = bq * 2, c1 = bq * 2 + 1;
        *(uint4*)((char*)Bs + brow * 128 + ((c0 ^ (brow & 7)) << 4)) = p0;
        *(uint4*)((char*)Bs + brow * 128 + ((c1 ^ (brow & 7)) << 4)) = p1;
        __syncthreads();
#pragma unroll
        for (int kc = 0; kc < 2; ++kc) {
            int kbyte = kc * 64 + fq * 16;
            int bn = w * 16 + fr;
            bf16x8 bfv = *(const bf16x8*)((const char*)Bs + bn * 128 +
                                          (kbyte ^ ((bn & 7) << 4)));
#pragma unroll
            for (int mi = 0; mi < 2; ++mi) {
                int am = mi * 16 + fr;
                bf16x8 af = *(const bf16x8*)((const char*)As + am * 128 +
                                             (kbyte ^ ((am & 7) << 4)));
                acc[mi] = __builtin_amdgcn_mfma_f32_16x16x32_bf16(
                    af, bfv, acc[mi], 0, 0, 0);
            }
        }
        __syncthreads();
    }
#pragma unroll
    for (int mi = 0; mi < 2; ++mi)
#pragma unroll
        for (int r = 0; r < 4; ++r) {
            int m = mi * 16 + fq * 4 + r;
            int j = jt * 64 + w * 16 + fr;
            part[((size_t)ks * 32 + m) * 256 + j] = acc[mi][r];
        }
}

__global__ void maeeg_cls2_kernel(const float* __restrict__ part,
                                  const float* __restrict__ bc1,
                                  float* __restrict__ hid)
{
    const int b = blockIdx.x, j = threadIdx.x;
    float s = bc1[j];
    for (int ks = 0; ks < 128; ++ks) s += part[((size_t)ks * 32 + b) * 256 + j];
    hid[b * 256 + j] = fmaxf(s, 0.f);
}

__global__ void maeeg_cls3_kernel(const float* __restrict__ hid,
                                  const float* __restrict__ Wc2,
                                  const float* __restrict__ bc2,
                                  float* __restrict__ out)
{
    const int b = blockIdx.x, t = threadIdx.x;
    float v = hid[b * 256 + t] * Wc2[t];
#pragma unroll
    for (int off = 32; off; off >>= 1) v += __shfl_down(v, off);
    __shared__ float r[4];
    if ((t & 63) == 0) r[t >> 6] = v;
    __syncthreads();
    if (t == 0) {
        float s = r[0] + r[1] + r[2] + r[3] + bc2[0];
        out[b] = 1.f / (1.f + expf(-s));
    }
}

// ===========================================================================
extern "C" void kernel_launch(void* const* d_in, const int* in_sizes, int n_in,
                              void* d_out, int out_size, void* d_ws, size_t ws_size,
                              hipStream_t stream)
{
    (void)in_sizes; (void)n_in; (void)out_size; (void)ws_size;
    const float* x        = (const float*)d_in[0];
    const float* conv0_w  = (const float*)d_in[1];
    const float* conv0_b  = (const float*)d_in[2];
    const float* conv12_w = (const float*)d_in[3];
    const float* conv12_b = (const float*)d_in[4];
    const float* gn_g     = (const float*)d_in[5];
    const float* gn_b     = (const float*)d_in[6];
    const float* Wq       = (const float*)d_in[7];
    const float* Wk       = (const float*)d_in[8];
    const float* Wv       = (const float*)d_in[9];
    const float* Wo       = (const float*)d_in[10];
    const float* ln1_g    = (const float*)d_in[11];
    const float* ln1_b    = (const float*)d_in[12];
    const float* Wf1      = (const float*)d_in[13];
    const float* bf1      = (const float*)d_in[14];
    const float* Wf2      = (const float*)d_in[15];
    const float* bf2      = (const float*)d_in[16];
    const float* ln2_g    = (const float*)d_in[17];
    const float* ln2_b    = (const float*)d_in[18];
    const float* Wc1      = (const float*)d_in[19];
    const float* bc1      = (const float*)d_in[20];
    const float* Wc2      = (const float*)d_in[21];
    const float* bc2      = (const float*)d_in[22];
    float* out = (float*)d_out;

    // ---- workspace layout (bytes) ----
    char* wsb = (char*)d_ws;
    u16* WB0   = (u16*)(wsb + 0);          //   524,288
    u16* WB12  = (u16*)(wsb + 524288);     // 4,194,304
    u16* WQKVb = (u16*)(wsb + 4718592);    // 1,572,864 [L][3][256][256]
    u16* WOb   = (u16*)(wsb + 6291456);    //   524,288
    u16* WF1b  = (u16*)(wsb + 6815744);    // 2,097,152
    u16* WF2b  = (u16*)(wsb + 8912896);    // 2,097,152 -> 11,010,048
    // R1: XPAD -> GN1B -> D
    u16*   XPAD  = (u16*)(wsb + 11010048);
    u16*   GN1B  = (u16*)(wsb + 11010048);
    float* D     = (float*)(wsb + 11010048);
    // R2 (67,108,864): CONV0 -> CONV1/CONV2 -> QKV/ATT/Db -> F1b
    float* CONV0 = (float*)(wsb + 28049408);
    float* CONV1 = (float*)(wsb + 28049408);
    float* CONV2 = (float*)(wsb + 28049408 + 33554432);
    u16*   Qb2   = (u16*)(wsb + 28049408);              // +0 (QKV packed base)
    u16*   ATTb  = (u16*)(wsb + 28049408 + 25165824);
    u16*   Db    = (u16*)(wsb + 28049408 + 33554432);
    u16*   F1b   = (u16*)(wsb + 28049408);
    // R3: GN0B -> C + Cb
    u16*   GN0B  = (u16*)(wsb + 95158272);
    float* C     = (float*)(wsb + 95158272);
    u16*   Cb    = (u16*)(wsb + 95158272 + 16777216);   // == flat bf16
    // R4
    float* PART  = (float*)(wsb + 128974848);           // 4,194,304
    float* HID   = (float*)(wsb + 133169152);           //    32,768
    float* PET   = (float*)(wsb + 133201920);           //   524,288

    // ---- weight prep ----
    maeeg_prep_convw_kernel<<<1024, 256, 0, stream>>>(conv0_w, WB0, 262144);
    maeeg_prep_convw_kernel<<<8192, 256, 0, stream>>>(conv12_w, WB12, 2097152);
    maeeg_cast_qkv_kernel<<<1024, 256, 0, stream>>>(Wq, WQKVb, 0);
    maeeg_cast_qkv_kernel<<<1024, 256, 0, stream>>>(Wk, WQKVb, 1);
    maeeg_cast_qkv_kernel<<<1024, 256, 0, stream>>>(Wv, WQKVb, 2);
    maeeg_cast_kernel<<<1024, 256, 0, stream>>>(Wo, WOb, 262144);
    maeeg_cast_kernel<<<4096, 256, 0, stream>>>(Wf1, WF1b, 1048576);
    maeeg_cast_kernel<<<4096, 256, 0, stream>>>(Wf2, WF2b, 1048576);
    maeeg_cast_pad_kernel<<<dim3(17, 2048), 256, 0, stream>>>(x, XPAD, 4096);
    maeeg_pe_kernel<<<512, 256, 0, stream>>>(PET);

    // ---- conv encoder ----
    maeeg_convmm_kernel<<<dim3(2, 16, 32), 256, 0, stream>>>(
        WB0, XPAD, conv0_b, CONV0, 1024, 4096, 2048);
    maeeg_gn_gelu_kernel<<<dim3(128, 32), 256, 0, stream>>>(
        CONV0, gn_g, gn_b, 2048, GN0B, 2064);
    maeeg_convmm_kernel<<<dim3(2, 8, 32), 256, 0, stream>>>(
        WB12, GN0B, conv12_b, CONV1, 4096, 2048, 1024);
    maeeg_gn_gelu_kernel<<<dim3(128, 32), 256, 0, stream>>>(
        CONV1, gn_g + 256, gn_b + 256, 1024, GN1B, 1040);
    maeeg_convmm_kernel<<<dim3(2, 4, 32), 256, 0, stream>>>(
        WB12 + 256 * 4096, GN1B, conv12_b + 256, CONV2, 4096, 1024, 512);
    maeeg_gn_gelu_kernel<<<dim3(128, 32), 256, 0, stream>>>(
        CONV2, gn_g + 512, gn_b + 512, 512, (u16*)0, 0);
    maeeg_transpose_pos_kernel<<<dim3(16, 32), 256, 0, stream>>>(CONV2, PET, C, Cb);

    // ---- transformer encoder ----
    for (int l = 0; l < 4; ++l) {
        maeeg_mm_kernel<<<dim3(128, 6), 256, 0, stream>>>(
            Cb, WQKVb + l * 196608, (const float*)0, (const float*)0,
            Qb2, 256, 256, 16);
        maeeg_fattn_kernel<<<dim3(4, 8, 32), 256, 0, stream>>>(
            Qb2, Qb2 + 4194304, Qb2 + 8388608, ATTb);
        maeeg_mm_kernel<<<dim3(128, 2), 256, 0, stream>>>(
            ATTb, WOb + l * 65536, (const float*)0, C, D, 256, 256, 0);
        maeeg_ln_kernel<<<16384, 256, 0, stream>>>(
            D, D, Db, ln1_g + l * 256, ln1_b + l * 256);
        maeeg_mm_kernel<<<dim3(128, 8), 256, 0, stream>>>(
            Db, WF1b + l * 262144, bf1 + l * 1024, (const float*)0, F1b, 1024, 256, 3);
        maeeg_mm_kernel<<<dim3(128, 2), 256, 0, stream>>>(
            F1b, WF2b + l * 262144, bf2 + l * 256, D, C, 256, 1024, 0);
        maeeg_ln_kernel<<<16384, 256, 0, stream>>>(
            C, C, Cb, ln2_g + l * 256, ln2_b + l * 256);
    }

    // ---- classifier ----
    maeeg_cls1_kernel<<<dim3(128, 4), 256, 0, stream>>>(Cb, Wc1, PART);
    maeeg_cls2_kernel<<<32, 256, 0, stream>>>(PART, bc1, HID);
    maeeg_cls3_kernel<<<32, 256, 0, stream>>>(HID, Wc2, bc2, out);
}